// Round 5
// baseline (2325.226 us; speedup 1.0000x reference)
//
#include <hip/hip_runtime.h>
#include <hip/hip_bf16.h>
#include <math.h>

#define Dm 768
#define Tt 1024
#define Bb 2
#define Hh 12
#define DFF 4096
#define Ll 12
#define Vv 50257
#define ROWS (Bb*Tt)   // 2048
#define LN_EPS 1e-5f

typedef unsigned int uint;
typedef unsigned short ushort;
typedef float f32x4 __attribute__((ext_vector_type(4)));
typedef short bf16x8 __attribute__((ext_vector_type(8)));
typedef ushort us8 __attribute__((ext_vector_type(8)));

__device__ __forceinline__ ushort f2bf(float f) {
  uint u = __builtin_bit_cast(uint, f);
  u += 0x7FFFu + ((u >> 16) & 1u);   // RNE
  return (ushort)(u >> 16);
}

#define GLL(gp, lp)                                                          \
  __builtin_amdgcn_global_load_lds(                                          \
      (const __attribute__((address_space(1))) uint*)(gp),                   \
      (__attribute__((address_space(3))) uint*)(lp), 16, 0, 0)

// ---------------------------------------------------------------------------
// Embedding (fp32 residual stream)
// ---------------------------------------------------------------------------
__global__ __launch_bounds__(256) void embed_kernel(
    const int* __restrict__ idx, const float* __restrict__ tok,
    const float* __restrict__ pos, float* __restrict__ x) {
  const int row = blockIdx.x;
  const int t = row & (Tt - 1);
  const float* tsrc = tok + (size_t)idx[row] * Dm;
  const float* psrc = pos + (size_t)t * Dm;
  float* dst = x + (size_t)row * Dm;
  for (int i = threadIdx.x; i < Dm; i += 256) dst[i] = tsrc[i] + psrc[i];
}

// ---------------------------------------------------------------------------
// LayerNorm: fp32 in -> bf16 out (used once, after embed)
// ---------------------------------------------------------------------------
__global__ __launch_bounds__(256) void ln_kernel(
    const float* __restrict__ x, const float* __restrict__ w,
    const float* __restrict__ b, ushort* __restrict__ out) {
  const int row = blockIdx.x;
  const int tid = threadIdx.x;
  const float* src = x + (size_t)row * Dm;
  float v[3];
  float sum = 0.f, sq = 0.f;
#pragma unroll
  for (int i = 0; i < 3; i++) {
    v[i] = src[tid + i * 256];
    sum += v[i]; sq += v[i] * v[i];
  }
#pragma unroll
  for (int off = 32; off > 0; off >>= 1) {
    sum += __shfl_xor(sum, off);
    sq  += __shfl_xor(sq, off);
  }
  __shared__ float red[8];
  const int wid = tid >> 6, lane = tid & 63;
  if (lane == 0) { red[wid] = sum; red[wid + 4] = sq; }
  __syncthreads();
  sum = red[0] + red[1] + red[2] + red[3];
  sq  = red[4] + red[5] + red[6] + red[7];
  const float mu = sum * (1.f / Dm);
  const float var = sq * (1.f / Dm) - mu * mu;
  const float rstd = rsqrtf(var + LN_EPS);
  ushort* dst = out + (size_t)row * Dm;
#pragma unroll
  for (int i = 0; i < 3; i++) {
    const int d = tid + i * 256;
    dst[d] = f2bf((v[i] - mu) * rstd * w[d] + b[d]);
  }
}

// ---------------------------------------------------------------------------
// Fused split-K reduce + bias + residual (x += ...) + LayerNorm -> bf16 h
// ---------------------------------------------------------------------------
__global__ __launch_bounds__(256) void red_ln(
    const float* __restrict__ part, int nsk, const float* __restrict__ bias,
    float* __restrict__ x, const float* __restrict__ w,
    const float* __restrict__ b, ushort* __restrict__ out) {
  const int row = blockIdx.x;
  const int tid = threadIdx.x;
  float v[3];
  float sum = 0.f, sq = 0.f;
#pragma unroll
  for (int i = 0; i < 3; i++) {
    const int d = tid + i * 256;
    const size_t off = (size_t)row * Dm + d;
    float s = x[off] + bias[d];
    for (int k = 0; k < nsk; k++) s += part[(size_t)k * ROWS * Dm + off];
    x[off] = s;
    v[i] = s;
    sum += s; sq += s * s;
  }
#pragma unroll
  for (int off = 32; off > 0; off >>= 1) {
    sum += __shfl_xor(sum, off);
    sq  += __shfl_xor(sq, off);
  }
  __shared__ float red[8];
  const int wid = tid >> 6, lane = tid & 63;
  if (lane == 0) { red[wid] = sum; red[wid + 4] = sq; }
  __syncthreads();
  sum = red[0] + red[1] + red[2] + red[3];
  sq  = red[4] + red[5] + red[6] + red[7];
  const float mu = sum * (1.f / Dm);
  const float var = sq * (1.f / Dm) - mu * mu;
  const float rstd = rsqrtf(var + LN_EPS);
  ushort* dst = out + (size_t)row * Dm;
#pragma unroll
  for (int i = 0; i < 3; i++) {
    const int d = tid + i * 256;
    dst[d] = f2bf((v[i] - mu) * rstd * w[d] + b[d]);
  }
}

// ---------------------------------------------------------------------------
// One-shot weight conversion fp32->bf16 for ALL layers + head.
// dst layout: per-layer [qkv|proj|ff1|ff2] blocks, then head flat.
// All counts in float4 units.
// ---------------------------------------------------------------------------
#define LW4 2162688          // layer stride (8650752 elems / 4)
#define SQ4 5308416          // 12 * 442368 (qkv)
#define SP4 1769472          // 12 * 147456 (proj)
#define SF4 9437184          // 12 * 786432 (ff1 and ff2)
#define SH4 9649344          // head 50257*768/4
#define CUM1 (SQ4)
#define CUM2 (SQ4+SP4)
#define CUM3 (SQ4+SP4+SF4)
#define CUM4 (SQ4+SP4+2*SF4)
#define N4ALL (SQ4+SP4+2*SF4+SH4)
#define HEADB4 25952256      // 12 * LW4

__global__ __launch_bounds__(256) void convert_gpt(
    const float* __restrict__ qkvw, const float* __restrict__ projw,
    const float* __restrict__ ff1w, const float* __restrict__ ff2w,
    const float* __restrict__ headw, ushort* __restrict__ wb) {
  const int stride = gridDim.x * 256;
  for (int i = blockIdx.x * 256 + threadIdx.x; i < N4ALL; i += stride) {
    const float* s; size_t d4;
    if (i < CUM1) {
      const int j = i, l = j / 442368, o = j - l * 442368;
      s = qkvw + (size_t)j * 4;
      d4 = (size_t)l * LW4 + o;
    } else if (i < CUM2) {
      const int j = i - CUM1, l = j / 147456, o = j - l * 147456;
      s = projw + (size_t)j * 4;
      d4 = (size_t)l * LW4 + 442368 + o;
    } else if (i < CUM3) {
      const int j = i - CUM2, l = j / 786432, o = j - l * 786432;
      s = ff1w + (size_t)j * 4;
      d4 = (size_t)l * LW4 + 589824 + o;
    } else if (i < CUM4) {
      const int j = i - CUM3, l = j / 786432, o = j - l * 786432;
      s = ff2w + (size_t)j * 4;
      d4 = (size_t)l * LW4 + 1376256 + o;
    } else {
      const int j = i - CUM4;
      s = headw + (size_t)j * 4;
      d4 = (size_t)HEADB4 + j;
    }
    const float4 v = *(const float4*)s;
    ushort4 o4;
    o4.x = f2bf(v.x); o4.y = f2bf(v.y); o4.z = f2bf(v.z); o4.w = f2bf(v.w);
    ((ushort4*)wb)[d4] = o4;
  }
}

// ---------------------------------------------------------------------------
// bf16 MFMA GEMM: C[M,Nloc] = A[M,Kloop]@B^T + epi.  Kstr = row stride.
// XCD-chunked bijective swizzle (m204): tiles linearized panel-major so each
// XCD works m-consecutive tiles of one B-panel -> panel stays in its L2.
// EPI_PART: blockIdx.z = split-k index; writes fp32 partial [z][row][Nloc].
// ---------------------------------------------------------------------------
#define EPI_QKV 0
#define EPI_PART 1
#define EPI_BIAS_GELU 2
#define EPI_NONE 3

template <int EPI>
__global__ __launch_bounds__(256) void gemm_mfma(
    const ushort* __restrict__ A, const ushort* __restrict__ B,
    const float* __restrict__ bias, void* __restrict__ Cv,
    int Kloop, int Kstr, int Nloc, int ldC) {
  __shared__ char lds[32768];           // 2 x (A 8KB + B 8KB)
  const int tid = threadIdx.x;
  const int l = tid & 63;
  const int wid = __builtin_amdgcn_readfirstlane(tid >> 6);
  const int wr = wid >> 1, wc = wid & 1;

  // ---- XCD-chunked swizzle ----
  const int nbx = gridDim.x, nby = gridDim.y;
  const int nwg = nbx * nby;
  const int bid = blockIdx.y * nbx + blockIdx.x;
  const int xcd = bid & 7, loc = bid >> 3;
  const int q8 = nwg >> 3, r8 = nwg & 7;
  const int swz = (xcd < r8 ? xcd * (q8 + 1) : r8 * (q8 + 1) + (xcd - r8) * q8) + loc;
  const int pan = swz / nby, mrw = swz - pan * nby;
  const int m0 = mrw * 128;
  const int n0 = pan * 128;

  const int z = (EPI == EPI_PART) ? blockIdx.z : 0;
  if (EPI == EPI_PART) { A += (size_t)z * Kloop; B += (size_t)z * Kloop; }

  const int cperm = (((l & 3) ^ ((l >> 3) & 3)) * 8);
  const ushort* gA = A + (size_t)(m0 + wid * 32 + (l >> 2)) * Kstr + cperm;
  int rB = n0 + wid * 32 + (l >> 2);
  rB = min(rB, Nloc - 1);
  const ushort* gB = B + (size_t)rB * Kstr + cperm;

  const int rdSw = (l & 15) * 64 + (((l >> 4) ^ ((l >> 1) & 3)) * 16);
  const int aRd = wr * 4096 + rdSw;
  const int bRd = 8192 + wc * 4096 + rdSw;

  f32x4 acc[4][4] = {};
  const int nt = Kloop / 32;

  {
    const int lb = wid * 2048;
    GLL(gA, lds + lb);          GLL(gA + 16 * Kstr, lds + lb + 1024);
    GLL(gB, lds + 8192 + lb);   GLL(gB + 16 * Kstr, lds + 8192 + lb + 1024);
  }

  for (int t = 0; t < nt; ++t) {
    __syncthreads();
    if (t + 1 < nt) {
      const int base = ((t + 1) & 1) * 16384;
      const int lb = base + wid * 2048;
      const ushort* a = gA + (t + 1) * 32;
      const ushort* b = gB + (t + 1) * 32;
      GLL(a, lds + lb);         GLL(a + 16 * Kstr, lds + lb + 1024);
      GLL(b, lds + 8192 + lb);  GLL(b + 16 * Kstr, lds + 8192 + lb + 1024);
    }
    const int base = (t & 1) * 16384;
    bf16x8 av[4], bv[4];
#pragma unroll
    for (int i = 0; i < 4; ++i) {
      av[i] = *(const bf16x8*)(lds + base + aRd + i * 1024);
      bv[i] = *(const bf16x8*)(lds + base + bRd + i * 1024);
    }
#pragma unroll
    for (int i = 0; i < 4; ++i)
#pragma unroll
      for (int j = 0; j < 4; ++j)
        acc[i][j] = __builtin_amdgcn_mfma_f32_16x16x32_bf16(
            av[i], bv[j], acc[i][j], 0, 0, 0);
  }

#pragma unroll
  for (int fm = 0; fm < 4; ++fm) {
    const int row0 = m0 + wr * 64 + fm * 16 + (l >> 4) * 4;
#pragma unroll
    for (int fn = 0; fn < 4; ++fn) {
      const int col = n0 + wc * 64 + fn * 16 + (l & 15);
      if (col >= Nloc) continue;
      float bi = 0.f;
      if (EPI == EPI_QKV || EPI == EPI_BIAS_GELU) bi = bias[col];
#pragma unroll
      for (int r = 0; r < 4; ++r) {
        float v = acc[fm][fn][r] + bi;
        const size_t off = (size_t)(row0 + r) * ldC + col;
        if (EPI == EPI_BIAS_GELU) {
          v = 0.5f * v * (1.f + erff(v * 0.70710678118654752f));
          ((ushort*)Cv)[off] = f2bf(v);
        } else if (EPI == EPI_QKV) {
          ((ushort*)Cv)[off] = f2bf(v);
        } else if (EPI == EPI_PART) {
          ((float*)Cv)[(size_t)z * ROWS * ldC + off] = v;
        } else {
          ((float*)Cv)[off] = v;
        }
      }
    }
  }
}

// ---------------------------------------------------------------------------
// V transpose: qkv V-part [t][d] -> vT [bh][d][t]
// ---------------------------------------------------------------------------
__global__ __launch_bounds__(256) void transpose_v(
    const ushort* __restrict__ qkv, ushort* __restrict__ vTg) {
  __shared__ ushort tile[64][65];
  const int tc = blockIdx.x, bh = blockIdx.y;
  const int b = bh / Hh, h = bh - b * Hh;
  const int tid = threadIdx.x;
#pragma unroll
  for (int i = 0; i < 2; i++) {
    const int c = tid + i * 256;
    const int t = c >> 3, d0 = (c & 7) * 8;
    us8 v = *(const us8*)(qkv + (size_t)(b * Tt + tc * 64 + t) * 2304 +
                          2 * Dm + h * 64 + d0);
#pragma unroll
    for (int j = 0; j < 8; j++) tile[t][d0 + j] = v[j];
  }
  __syncthreads();
#pragma unroll
  for (int i = 0; i < 2; i++) {
    const int c = tid + i * 256;
    const int d = c >> 3, t0 = (c & 7) * 8;
    us8 o;
#pragma unroll
    for (int j = 0; j < 8; j++) o[j] = tile[t0 + j][d];
    *(us8*)(vTg + (size_t)(bh * 64 + d) * Tt + tc * 64 + t0) = o;
  }
}

// ---------------------------------------------------------------------------
// MFMA flash attention. 128 thr = 2 waves; wave w owns q-rows bq*32+w*16..+15.
// ---------------------------------------------------------------------------
__global__ __launch_bounds__(128) void attn_mfma(
    const ushort* __restrict__ qkv, const ushort* __restrict__ vTg,
    ushort* __restrict__ y) {
  __shared__ char lds[36864];   // 2 x {K 8KB, VT 8KB} + P 2x2KB
  const int tid = threadIdx.x;
  const int l = tid & 63;
  const int w = tid >> 6;
  const int s = l & 15, g = l >> 4;
  const int bq = blockIdx.x, h = blockIdx.y, b = blockIdx.z;
  const int bh = b * Hh + h;

  const int qrow = bq * 32 + w * 16 + s;
  const ushort* qp = qkv + (size_t)(b * Tt + qrow) * 2304 + h * 64 + g * 8;
  const bf16x8 aq0 = *(const bf16x8*)qp;
  const bf16x8 aq1 = *(const bf16x8*)(qp + 32);

  size_t gofs[8];
#pragma unroll
  for (int i = 0; i < 8; i++) {
    const int c = tid + i * 128;
    if (i < 4) {
      const int kr = c >> 3;
      gofs[i] = (size_t)(b * Tt + kr) * 2304 + Dm + h * 64 + ((c & 7) ^ (kr & 7)) * 8;
    } else {
      const int cv = c - 512;
      const int vr = cv >> 3;
      gofs[i] = (size_t)(bh * 64 + vr) * Tt + ((cv & 7) ^ (vr & 7)) * 8;
    }
  }

#define ASTAGE(kt, base)                                                     \
  do {                                                                       \
    _Pragma("unroll")                                                        \
    for (int i = 0; i < 8; i++) {                                            \
      const ushort* p = (i < 4) ? (qkv + gofs[i] + (size_t)(kt) * 147456)    \
                                : (vTg + gofs[i] + (kt) * 64);               \
      GLL(p, lds + (base) + tid * 16 + i * 2048);                            \
    }                                                                        \
  } while (0)

  f32x4 oc[4] = {};
  float mrun[4], lrun[4];
#pragma unroll
  for (int r = 0; r < 4; r++) { mrun[r] = -INFINITY; lrun[r] = 0.f; }

  const int pB = 32768 + w * 2048;
  const int kSw = (s & 7);
  const int nkt = (bq >> 1) + 1;

  ASTAGE(0, 0);
  for (int kt = 0; kt < nkt; ++kt) {
    __syncthreads();
    if (kt + 1 < nkt) ASTAGE(kt + 1, ((kt + 1) & 1) * 16384);
    const int cur = (kt & 1) * 16384;

    f32x4 sc[4];
#pragma unroll
    for (int jn = 0; jn < 4; jn++) {
      const int krow = cur + (jn * 16 + s) * 128;
      const bf16x8 bk0 = *(const bf16x8*)(lds + krow + ((g ^ kSw) * 16));
      const bf16x8 bk1 = *(const bf16x8*)(lds + krow + (((4 + g) ^ kSw) * 16));
      f32x4 z = {};
      z = __builtin_amdgcn_mfma_f32_16x16x32_bf16(aq0, bk0, z, 0, 0, 0);
      z = __builtin_amdgcn_mfma_f32_16x16x32_bf16(aq1, bk1, z, 0, 0, 0);
      sc[jn] = z;
    }

    float cr[4];
    const bool diag = (kt == nkt - 1);
#pragma unroll
    for (int r = 0; r < 4; r++) {
      const int rowg = bq * 32 + w * 16 + g * 4 + r;
      float v[4];
#pragma unroll
      for (int jn = 0; jn < 4; jn++) {
        v[jn] = sc[jn][r] * 0.125f;
        if (diag && (kt * 64 + jn * 16 + s) > rowg) v[jn] = -INFINITY;
      }
      float mx = fmaxf(fmaxf(v[0], v[1]), fmaxf(v[2], v[3]));
      mx = fmaxf(mx, __shfl_xor(mx, 1));
      mx = fmaxf(mx, __shfl_xor(mx, 2));
      mx = fmaxf(mx, __shfl_xor(mx, 4));
      mx = fmaxf(mx, __shfl_xor(mx, 8));
      const float mnew = fmaxf(mrun[r], mx);
      const float corr = __expf(mrun[r] - mnew);
      mrun[r] = mnew;
      float ps = 0.f;
#pragma unroll
      for (int jn = 0; jn < 4; jn++) {
        const float p = __expf(v[jn] - mnew);
        ps += p;
        *(ushort*)(lds + pB + (g * 4 + r) * 128 +
                   (((2 * jn + (s >> 3)) ^ g) * 16) + (s & 7) * 2) = f2bf(p);
      }
      ps += __shfl_xor(ps, 1);
      ps += __shfl_xor(ps, 2);
      ps += __shfl_xor(ps, 4);
      ps += __shfl_xor(ps, 8);
      lrun[r] = lrun[r] * corr + ps;
      cr[r] = corr;
    }

    const float c01 = (s & 1) ? cr[1] : cr[0];
    const float c23 = (s & 1) ? cr[3] : cr[2];
    const float csel = (s & 2) ? c23 : c01;
    const float ccol = __shfl(csel, ((s >> 2) << 4) | s);
#pragma unroll
    for (int fm = 0; fm < 4; fm++) {
      oc[fm][0] *= ccol; oc[fm][1] *= ccol;
      oc[fm][2] *= ccol; oc[fm][3] *= ccol;
    }

    const bf16x8 bp0 = *(const bf16x8*)(lds + pB + s * 128 + ((g ^ (s >> 2)) * 16));
    const bf16x8 bp1 = *(const bf16x8*)(lds + pB + s * 128 + (((4 + g) ^ (s >> 2)) * 16));
#pragma unroll
    for (int fm = 0; fm < 4; fm++) {
      const int vrow = cur + 8192 + (fm * 16 + s) * 128;
      const bf16x8 av0 = *(const bf16x8*)(lds + vrow + ((g ^ kSw) * 16));
      const bf16x8 av1 = *(const bf16x8*)(lds + vrow + (((4 + g) ^ kSw) * 16));
      oc[fm] = __builtin_amdgcn_mfma_f32_16x16x32_bf16(av0, bp0, oc[fm], 0, 0, 0);
      oc[fm] = __builtin_amdgcn_mfma_f32_16x16x32_bf16(av1, bp1, oc[fm], 0, 0, 0);
    }
  }

  float li[4];
#pragma unroll
  for (int r = 0; r < 4; r++) li[r] = 1.f / lrun[r];
  const float l01 = (s & 1) ? li[1] : li[0];
  const float l23 = (s & 1) ? li[3] : li[2];
  const float lsel = (s & 2) ? l23 : l01;
  const float lcol = __shfl(lsel, ((s >> 2) << 4) | s);
  ushort* yp = y + (size_t)(b * Tt + qrow) * Dm + h * 64;
#pragma unroll
  for (int fm = 0; fm < 4; fm++) {
    ushort4 o4;
    o4.x = f2bf(oc[fm][0] * lcol);
    o4.y = f2bf(oc[fm][1] * lcol);
    o4.z = f2bf(oc[fm][2] * lcol);
    o4.w = f2bf(oc[fm][3] * lcol);
    *(ushort4*)(yp + fm * 16 + g * 4) = o4;
  }
}

// ---------------------------------------------------------------------------
extern "C" void kernel_launch(void* const* d_in, const int* in_sizes, int n_in,
                              void* d_out, int out_size, void* d_ws, size_t ws_size,
                              hipStream_t stream) {
  const int* idx = (const int*)d_in[0];
  const float* tok = (const float*)d_in[1];
  const float* pos = (const float*)d_in[2];
  const float* ln1w = (const float*)d_in[3];
  const float* ln1b = (const float*)d_in[4];
  const float* qkvw = (const float*)d_in[5];
  const float* qkvb = (const float*)d_in[6];
  const float* projw = (const float*)d_in[7];
  const float* projb = (const float*)d_in[8];
  const float* ln2w = (const float*)d_in[9];
  const float* ln2b = (const float*)d_in[10];
  const float* ff1w = (const float*)d_in[11];
  const float* ff1b = (const float*)d_in[12];
  const float* ff2w = (const float*)d_in[13];
  const float* ff2b = (const float*)d_in[14];
  const float* lnfw = (const float*)d_in[15];
  const float* lnfb = (const float*)d_in[16];
  const float* headw = (const float*)d_in[17];
  float* out = (float*)d_out;

  char* ws = (char*)d_ws;
  ushort* h    = (ushort*)ws;                    // [2048][768] bf16
  float*  x    = (float*)(ws + 3145728);         // [2048][768] fp32
  ushort* y    = (ushort*)(ws + 9437184);        // [2048][768] bf16
  ushort* qkv  = (ushort*)(ws + 12582912);       // [2048][2304] bf16
  ushort* vTg  = (ushort*)(ws + 22020096);       // [24][64][1024] bf16
  ushort* ff   = (ushort*)(ws + 25165824);       // [2048][4096] bf16
  ushort* wb   = (ushort*)(ws + 41943040);       // all weights bf16 (285MB)
  float* projPart = (float*)(ws + 12582912);     // 2x6.29MB over qkv+vT
  float* ff2Part  = (float*)(ws + 9437184);      // 2x6.29MB over y+qkv

  const int oProj = 3 * Dm * Dm;                 // 1769472
  const int oFF1  = oProj + Dm * Dm;             // 2359296
  const int oFF2  = oFF1 + DFF * Dm;             // 5505024
  const size_t LWE = 8650752;                    // layer weight stride (elems)
  ushort* headwb = wb + (size_t)HEADB4 * 4;

  convert_gpt<<<4096, 256, 0, stream>>>(qkvw, projw, ff1w, ff2w, headw, wb);
  embed_kernel<<<ROWS, 256, 0, stream>>>(idx, tok, pos, x);
  ln_kernel<<<ROWS, 256, 0, stream>>>(x, ln1w, ln1b, h);

  for (int l = 0; l < Ll; l++) {
    ushort* wl = wb + (size_t)l * LWE;
    gemm_mfma<EPI_QKV><<<dim3(18, 16), 256, 0, stream>>>(
        h, wl, qkvb + l * 3 * Dm, qkv, Dm, Dm, 3 * Dm, 3 * Dm);
    transpose_v<<<dim3(16, 24), 256, 0, stream>>>(qkv, vTg);
    attn_mfma<<<dim3(32, Hh, Bb), 128, 0, stream>>>(qkv, vTg, y);
    gemm_mfma<EPI_PART><<<dim3(6, 16, 2), 256, 0, stream>>>(
        y, wl + oProj, nullptr, projPart, Dm / 2, Dm, Dm, Dm);
    red_ln<<<ROWS, 256, 0, stream>>>(projPart, 2, projb + l * Dm, x,
                                     ln2w + l * Dm, ln2b + l * Dm, h);
    gemm_mfma<EPI_BIAS_GELU><<<dim3(32, 16), 256, 0, stream>>>(
        h, wl + oFF1, ff1b + l * DFF, ff, Dm, Dm, DFF, DFF);
    gemm_mfma<EPI_PART><<<dim3(6, 16, 2), 256, 0, stream>>>(
        ff, wl + oFF2, nullptr, ff2Part, DFF / 2, DFF, Dm, Dm);
    const float* nw = (l == Ll - 1) ? lnfw : ln1w + (l + 1) * Dm;
    const float* nb = (l == Ll - 1) ? lnfb : ln1b + (l + 1) * Dm;
    red_ln<<<ROWS, 256, 0, stream>>>(ff2Part, 2, ff2b + l * Dm, x, nw, nb, h);
  }

  gemm_mfma<EPI_NONE><<<dim3(393, 16), 256, 0, stream>>>(
      h, headwb, nullptr, out, Dm, Dm, Vv, Vv);
}

// Round 6
// 2245.162 us; speedup vs baseline: 1.0357x; 1.0357x over previous
//
#include <hip/hip_runtime.h>
#include <hip/hip_bf16.h>
#include <math.h>

#define Dm 768
#define Tt 1024
#define Bb 2
#define Hh 12
#define DFF 4096
#define Ll 12
#define Vv 50257
#define ROWS (Bb*Tt)   // 2048
#define LN_EPS 1e-5f

typedef unsigned int uint;
typedef unsigned short ushort;
typedef float f32x4 __attribute__((ext_vector_type(4)));
typedef short bf16x8 __attribute__((ext_vector_type(8)));
typedef ushort us8 __attribute__((ext_vector_type(8)));

__device__ __forceinline__ ushort f2bf(float f) {
  uint u = __builtin_bit_cast(uint, f);
  u += 0x7FFFu + ((u >> 16) & 1u);   // RNE
  return (ushort)(u >> 16);
}

#define GLL(gp, lp)                                                          \
  __builtin_amdgcn_global_load_lds(                                          \
      (const __attribute__((address_space(1))) uint*)(gp),                   \
      (__attribute__((address_space(3))) uint*)(lp), 16, 0, 0)

// ---------------------------------------------------------------------------
// Fused embedding + LayerNorm: x = tok[idx]+pos (fp32), h = LN(x) (bf16)
// ---------------------------------------------------------------------------
__global__ __launch_bounds__(256) void embed_ln(
    const int* __restrict__ idx, const float* __restrict__ tok,
    const float* __restrict__ pos, const float* __restrict__ w,
    const float* __restrict__ b, float* __restrict__ x,
    ushort* __restrict__ out) {
  const int row = blockIdx.x;
  const int t = row & (Tt - 1);
  const int tid = threadIdx.x;
  const float* tsrc = tok + (size_t)idx[row] * Dm;
  const float* psrc = pos + (size_t)t * Dm;
  float v[3];
  float sum = 0.f, sq = 0.f;
#pragma unroll
  for (int i = 0; i < 3; i++) {
    const int d = tid + i * 256;
    v[i] = tsrc[d] + psrc[d];
    x[(size_t)row * Dm + d] = v[i];
    sum += v[i]; sq += v[i] * v[i];
  }
#pragma unroll
  for (int off = 32; off > 0; off >>= 1) {
    sum += __shfl_xor(sum, off);
    sq  += __shfl_xor(sq, off);
  }
  __shared__ float red[8];
  const int wid = tid >> 6, lane = tid & 63;
  if (lane == 0) { red[wid] = sum; red[wid + 4] = sq; }
  __syncthreads();
  sum = red[0] + red[1] + red[2] + red[3];
  sq  = red[4] + red[5] + red[6] + red[7];
  const float mu = sum * (1.f / Dm);
  const float var = sq * (1.f / Dm) - mu * mu;
  const float rstd = rsqrtf(var + LN_EPS);
  ushort* dst = out + (size_t)row * Dm;
#pragma unroll
  for (int i = 0; i < 3; i++) {
    const int d = tid + i * 256;
    dst[d] = f2bf((v[i] - mu) * rstd * w[d] + b[d]);
  }
}

// ---------------------------------------------------------------------------
// Fused split-K reduce + bias + residual (x += ...) + LayerNorm -> bf16 h
// ---------------------------------------------------------------------------
__global__ __launch_bounds__(256) void red_ln(
    const float* __restrict__ part, int nsk, const float* __restrict__ bias,
    float* __restrict__ x, const float* __restrict__ w,
    const float* __restrict__ b, ushort* __restrict__ out) {
  const int row = blockIdx.x;
  const int tid = threadIdx.x;
  float v[3];
  float sum = 0.f, sq = 0.f;
#pragma unroll
  for (int i = 0; i < 3; i++) {
    const int d = tid + i * 256;
    const size_t off = (size_t)row * Dm + d;
    float s = x[off] + bias[d];
    for (int k = 0; k < nsk; k++) s += part[(size_t)k * ROWS * Dm + off];
    x[off] = s;
    v[i] = s;
    sum += s; sq += s * s;
  }
#pragma unroll
  for (int off = 32; off > 0; off >>= 1) {
    sum += __shfl_xor(sum, off);
    sq  += __shfl_xor(sq, off);
  }
  __shared__ float red[8];
  const int wid = tid >> 6, lane = tid & 63;
  if (lane == 0) { red[wid] = sum; red[wid + 4] = sq; }
  __syncthreads();
  sum = red[0] + red[1] + red[2] + red[3];
  sq  = red[4] + red[5] + red[6] + red[7];
  const float mu = sum * (1.f / Dm);
  const float var = sq * (1.f / Dm) - mu * mu;
  const float rstd = rsqrtf(var + LN_EPS);
  ushort* dst = out + (size_t)row * Dm;
#pragma unroll
  for (int i = 0; i < 3; i++) {
    const int d = tid + i * 256;
    dst[d] = f2bf((v[i] - mu) * rstd * w[d] + b[d]);
  }
}

// ---------------------------------------------------------------------------
// Weight converter fp32 -> bf16 (count in float4 units, contiguous)
// ---------------------------------------------------------------------------
__global__ __launch_bounds__(256) void convert_w(
    const float* __restrict__ s, ushort* __restrict__ d, int n4) {
  const int stride = gridDim.x * 256;
  for (int i = blockIdx.x * 256 + threadIdx.x; i < n4; i += stride) {
    const float4 v = ((const float4*)s)[i];
    ushort4 o;
    o.x = f2bf(v.x); o.y = f2bf(v.y); o.z = f2bf(v.z); o.w = f2bf(v.w);
    ((ushort4*)d)[i] = o;
  }
}

// ---------------------------------------------------------------------------
// bf16 MFMA GEMM: C[M,Nloc] = A[M,Kloop]@B^T + epi.  Kstr = row stride.
// EPI_QKV: cols<1536 -> qkv buf; cols>=1536 (V) -> transposed into vT (Cv2).
// EPI_PART: blockIdx.z = split-k index; writes fp32 partial [z][row][Nloc].
// ---------------------------------------------------------------------------
#define EPI_QKV 0
#define EPI_PART 1
#define EPI_BIAS_GELU 2
#define EPI_NONE 3

template <int EPI>
__global__ __launch_bounds__(256) void gemm_mfma(
    const ushort* __restrict__ A, const ushort* __restrict__ B,
    const float* __restrict__ bias, void* __restrict__ Cv,
    void* __restrict__ Cv2, int Kloop, int Kstr, int Nloc, int ldC) {
  __shared__ char lds[32768];           // 2 x (A 8KB + B 8KB)
  const int tid = threadIdx.x;
  const int l = tid & 63;
  const int wid = __builtin_amdgcn_readfirstlane(tid >> 6);
  const int wr = wid >> 1, wc = wid & 1;
  const int m0 = blockIdx.y * 128;
  const int n0 = blockIdx.x * 128;
  const int z = (EPI == EPI_PART) ? blockIdx.z : 0;
  if (EPI == EPI_PART) { A += (size_t)z * Kloop; B += (size_t)z * Kloop; }

  const int cperm = (((l & 3) ^ ((l >> 3) & 3)) * 8);
  const ushort* gA = A + (size_t)(m0 + wid * 32 + (l >> 2)) * Kstr + cperm;
  int rB = n0 + wid * 32 + (l >> 2);
  rB = min(rB, Nloc - 1);
  const ushort* gB = B + (size_t)rB * Kstr + cperm;

  const int rdSw = (l & 15) * 64 + (((l >> 4) ^ ((l >> 1) & 3)) * 16);
  const int aRd = wr * 4096 + rdSw;
  const int bRd = 8192 + wc * 4096 + rdSw;

  f32x4 acc[4][4] = {};
  const int nt = Kloop / 32;

  {
    const int lb = wid * 2048;
    GLL(gA, lds + lb);          GLL(gA + 16 * Kstr, lds + lb + 1024);
    GLL(gB, lds + 8192 + lb);   GLL(gB + 16 * Kstr, lds + 8192 + lb + 1024);
  }

  for (int t = 0; t < nt; ++t) {
    __syncthreads();
    if (t + 1 < nt) {
      const int base = ((t + 1) & 1) * 16384;
      const int lb = base + wid * 2048;
      const ushort* a = gA + (t + 1) * 32;
      const ushort* b = gB + (t + 1) * 32;
      GLL(a, lds + lb);         GLL(a + 16 * Kstr, lds + lb + 1024);
      GLL(b, lds + 8192 + lb);  GLL(b + 16 * Kstr, lds + 8192 + lb + 1024);
    }
    const int base = (t & 1) * 16384;
    bf16x8 av[4], bv[4];
#pragma unroll
    for (int i = 0; i < 4; ++i) {
      av[i] = *(const bf16x8*)(lds + base + aRd + i * 1024);
      bv[i] = *(const bf16x8*)(lds + base + bRd + i * 1024);
    }
#pragma unroll
    for (int i = 0; i < 4; ++i)
#pragma unroll
      for (int j = 0; j < 4; ++j)
        acc[i][j] = __builtin_amdgcn_mfma_f32_16x16x32_bf16(
            av[i], bv[j], acc[i][j], 0, 0, 0);
  }

#pragma unroll
  for (int fm = 0; fm < 4; ++fm) {
    const int row0 = m0 + wr * 64 + fm * 16 + (l >> 4) * 4;
#pragma unroll
    for (int fn = 0; fn < 4; ++fn) {
      const int col = n0 + wc * 64 + fn * 16 + (l & 15);
      if (col >= Nloc) continue;
      float bi = 0.f;
      if (EPI == EPI_QKV || EPI == EPI_BIAS_GELU) bi = bias[col];
      if (EPI == EPI_QKV && col >= 2 * Dm) {
        // V part -> write transposed: vT[(b*Hh+h)*64+d][t], 4 consecutive t
        const int hh = (col - 2 * Dm) >> 6, dd = col & 63;
        const int bI = row0 >> 10, t0 = row0 & (Tt - 1);
        ushort4 o4;
        o4.x = f2bf(acc[fm][fn][0] + bi);
        o4.y = f2bf(acc[fm][fn][1] + bi);
        o4.z = f2bf(acc[fm][fn][2] + bi);
        o4.w = f2bf(acc[fm][fn][3] + bi);
        *(ushort4*)((ushort*)Cv2 +
                    ((size_t)((bI * Hh + hh) * 64 + dd)) * Tt + t0) = o4;
        continue;
      }
#pragma unroll
      for (int r = 0; r < 4; ++r) {
        float v = acc[fm][fn][r] + bi;
        const size_t off = (size_t)(row0 + r) * ldC + col;
        if (EPI == EPI_BIAS_GELU) {
          v = 0.5f * v * (1.f + erff(v * 0.70710678118654752f));
          ((ushort*)Cv)[off] = f2bf(v);
        } else if (EPI == EPI_QKV) {
          ((ushort*)Cv)[off] = f2bf(v);
        } else if (EPI == EPI_PART) {
          ((float*)Cv)[(size_t)z * ROWS * ldC + off] = v;
        } else {
          ((float*)Cv)[off] = v;
        }
      }
    }
  }
}

// ---------------------------------------------------------------------------
// MFMA flash attention. 128 thr = 2 waves; wave w owns q-rows bq*32+w*16..+15.
// ---------------------------------------------------------------------------
__global__ __launch_bounds__(128) void attn_mfma(
    const ushort* __restrict__ qkv, const ushort* __restrict__ vTg,
    ushort* __restrict__ y) {
  __shared__ char lds[36864];   // 2 x {K 8KB, VT 8KB} + P 2x2KB
  const int tid = threadIdx.x;
  const int l = tid & 63;
  const int w = tid >> 6;
  const int s = l & 15, g = l >> 4;
  const int bq = blockIdx.x, h = blockIdx.y, b = blockIdx.z;
  const int bh = b * Hh + h;

  const int qrow = bq * 32 + w * 16 + s;
  const ushort* qp = qkv + (size_t)(b * Tt + qrow) * 2304 + h * 64 + g * 8;
  const bf16x8 aq0 = *(const bf16x8*)qp;
  const bf16x8 aq1 = *(const bf16x8*)(qp + 32);

  size_t gofs[8];
#pragma unroll
  for (int i = 0; i < 8; i++) {
    const int c = tid + i * 128;
    if (i < 4) {
      const int kr = c >> 3;
      gofs[i] = (size_t)(b * Tt + kr) * 2304 + Dm + h * 64 + ((c & 7) ^ (kr & 7)) * 8;
    } else {
      const int cv = c - 512;
      const int vr = cv >> 3;
      gofs[i] = (size_t)(bh * 64 + vr) * Tt + ((cv & 7) ^ (vr & 7)) * 8;
    }
  }

#define ASTAGE(kt, base)                                                     \
  do {                                                                       \
    _Pragma("unroll")                                                        \
    for (int i = 0; i < 8; i++) {                                            \
      const ushort* p = (i < 4) ? (qkv + gofs[i] + (size_t)(kt) * 147456)    \
                                : (vTg + gofs[i] + (kt) * 64);               \
      GLL(p, lds + (base) + tid * 16 + i * 2048);                            \
    }                                                                        \
  } while (0)

  f32x4 oc[4] = {};
  float mrun[4], lrun[4];
#pragma unroll
  for (int r = 0; r < 4; r++) { mrun[r] = -INFINITY; lrun[r] = 0.f; }

  const int pB = 32768 + w * 2048;
  const int kSw = (s & 7);
  const int nkt = (bq >> 1) + 1;

  ASTAGE(0, 0);
  for (int kt = 0; kt < nkt; ++kt) {
    __syncthreads();
    if (kt + 1 < nkt) ASTAGE(kt + 1, ((kt + 1) & 1) * 16384);
    const int cur = (kt & 1) * 16384;

    f32x4 sc[4];
#pragma unroll
    for (int jn = 0; jn < 4; jn++) {
      const int krow = cur + (jn * 16 + s) * 128;
      const bf16x8 bk0 = *(const bf16x8*)(lds + krow + ((g ^ kSw) * 16));
      const bf16x8 bk1 = *(const bf16x8*)(lds + krow + (((4 + g) ^ kSw) * 16));
      f32x4 z = {};
      z = __builtin_amdgcn_mfma_f32_16x16x32_bf16(aq0, bk0, z, 0, 0, 0);
      z = __builtin_amdgcn_mfma_f32_16x16x32_bf16(aq1, bk1, z, 0, 0, 0);
      sc[jn] = z;
    }

    float cr[4];
    const bool diag = (kt == nkt - 1);
#pragma unroll
    for (int r = 0; r < 4; r++) {
      const int rowg = bq * 32 + w * 16 + g * 4 + r;
      float v[4];
#pragma unroll
      for (int jn = 0; jn < 4; jn++) {
        v[jn] = sc[jn][r] * 0.125f;
        if (diag && (kt * 64 + jn * 16 + s) > rowg) v[jn] = -INFINITY;
      }
      float mx = fmaxf(fmaxf(v[0], v[1]), fmaxf(v[2], v[3]));
      mx = fmaxf(mx, __shfl_xor(mx, 1));
      mx = fmaxf(mx, __shfl_xor(mx, 2));
      mx = fmaxf(mx, __shfl_xor(mx, 4));
      mx = fmaxf(mx, __shfl_xor(mx, 8));
      const float mnew = fmaxf(mrun[r], mx);
      const float corr = __expf(mrun[r] - mnew);
      mrun[r] = mnew;
      float ps = 0.f;
#pragma unroll
      for (int jn = 0; jn < 4; jn++) {
        const float p = __expf(v[jn] - mnew);
        ps += p;
        *(ushort*)(lds + pB + (g * 4 + r) * 128 +
                   (((2 * jn + (s >> 3)) ^ g) * 16) + (s & 7) * 2) = f2bf(p);
      }
      ps += __shfl_xor(ps, 1);
      ps += __shfl_xor(ps, 2);
      ps += __shfl_xor(ps, 4);
      ps += __shfl_xor(ps, 8);
      lrun[r] = lrun[r] * corr + ps;
      cr[r] = corr;
    }

    const float c01 = (s & 1) ? cr[1] : cr[0];
    const float c23 = (s & 1) ? cr[3] : cr[2];
    const float csel = (s & 2) ? c23 : c01;
    const float ccol = __shfl(csel, ((s >> 2) << 4) | s);
#pragma unroll
    for (int fm = 0; fm < 4; fm++) {
      oc[fm][0] *= ccol; oc[fm][1] *= ccol;
      oc[fm][2] *= ccol; oc[fm][3] *= ccol;
    }

    const bf16x8 bp0 = *(const bf16x8*)(lds + pB + s * 128 + ((g ^ (s >> 2)) * 16));
    const bf16x8 bp1 = *(const bf16x8*)(lds + pB + s * 128 + (((4 + g) ^ (s >> 2)) * 16));
#pragma unroll
    for (int fm = 0; fm < 4; fm++) {
      const int vrow = cur + 8192 + (fm * 16 + s) * 128;
      const bf16x8 av0 = *(const bf16x8*)(lds + vrow + ((g ^ kSw) * 16));
      const bf16x8 av1 = *(const bf16x8*)(lds + vrow + (((4 + g) ^ kSw) * 16));
      oc[fm] = __builtin_amdgcn_mfma_f32_16x16x32_bf16(av0, bp0, oc[fm], 0, 0, 0);
      oc[fm] = __builtin_amdgcn_mfma_f32_16x16x32_bf16(av1, bp1, oc[fm], 0, 0, 0);
    }
  }

  float li[4];
#pragma unroll
  for (int r = 0; r < 4; r++) li[r] = 1.f / lrun[r];
  const float l01 = (s & 1) ? li[1] : li[0];
  const float l23 = (s & 1) ? li[3] : li[2];
  const float lsel = (s & 2) ? l23 : l01;
  const float lcol = __shfl(lsel, ((s >> 2) << 4) | s);
  ushort* yp = y + (size_t)(b * Tt + qrow) * Dm + h * 64;
#pragma unroll
  for (int fm = 0; fm < 4; fm++) {
    ushort4 o4;
    o4.x = f2bf(oc[fm][0] * lcol);
    o4.y = f2bf(oc[fm][1] * lcol);
    o4.z = f2bf(oc[fm][2] * lcol);
    o4.w = f2bf(oc[fm][3] * lcol);
    *(ushort4*)(yp + fm * 16 + g * 4) = o4;
  }
}

// ---------------------------------------------------------------------------
extern "C" void kernel_launch(void* const* d_in, const int* in_sizes, int n_in,
                              void* d_out, int out_size, void* d_ws, size_t ws_size,
                              hipStream_t stream) {
  const int* idx = (const int*)d_in[0];
  const float* tok = (const float*)d_in[1];
  const float* pos = (const float*)d_in[2];
  const float* ln1w = (const float*)d_in[3];
  const float* ln1b = (const float*)d_in[4];
  const float* qkvw = (const float*)d_in[5];
  const float* qkvb = (const float*)d_in[6];
  const float* projw = (const float*)d_in[7];
  const float* projb = (const float*)d_in[8];
  const float* ln2w = (const float*)d_in[9];
  const float* ln2b = (const float*)d_in[10];
  const float* ff1w = (const float*)d_in[11];
  const float* ff1b = (const float*)d_in[12];
  const float* ff2w = (const float*)d_in[13];
  const float* ff2b = (const float*)d_in[14];
  const float* lnfw = (const float*)d_in[15];
  const float* lnfb = (const float*)d_in[16];
  const float* headw = (const float*)d_in[17];
  float* out = (float*)d_out;

  char* ws = (char*)d_ws;
  ushort* h    = (ushort*)ws;                    // [2048][768] bf16
  float*  x    = (float*)(ws + 3145728);         // [2048][768] fp32
  ushort* y    = (ushort*)(ws + 9437184);        // [2048][768] bf16
  ushort* qkv  = (ushort*)(ws + 12582912);       // [2048][2304] bf16
  ushort* vTg  = (ushort*)(ws + 22020096);       // [24][64][1024] bf16
  ushort* ff   = (ushort*)(ws + 25165824);       // [2048][4096] bf16
  ushort* wb   = (ushort*)(ws + 41943040);       // all weights bf16 (285MB)
  float* projPart = (float*)(ws + 12582912);     // 2x6.29MB over qkv+vT
  float* ff2Part  = (float*)(ws + 9437184);      // 2x6.29MB over y+qkv

  // per-tensor bf16 weight regions (element offsets into wb)
  const size_t oPROJ = (size_t)Ll * 3 * Dm * Dm;           // 21233664
  const size_t oFF1  = oPROJ + (size_t)Ll * Dm * Dm;       // 28311552
  const size_t oFF2  = oFF1 + (size_t)Ll * DFF * Dm;       // 66060288
  const size_t oHEAD = oFF2 + (size_t)Ll * Dm * DFF;       // 103809024

  convert_w<<<2048, 256, 0, stream>>>(qkvw, wb, (int)(oPROJ / 4));
  convert_w<<<2048, 256, 0, stream>>>(projw, wb + oPROJ, (int)((oFF1 - oPROJ) / 4));
  convert_w<<<2048, 256, 0, stream>>>(ff1w, wb + oFF1, (int)((oFF2 - oFF1) / 4));
  convert_w<<<2048, 256, 0, stream>>>(ff2w, wb + oFF2, (int)((oHEAD - oFF2) / 4));
  convert_w<<<2048, 256, 0, stream>>>(headw, wb + oHEAD, (int)((size_t)Vv * Dm / 4));

  embed_ln<<<ROWS, 256, 0, stream>>>(idx, tok, pos, ln1w, ln1b, x, h);

  for (int l = 0; l < Ll; l++) {
    gemm_mfma<EPI_QKV><<<dim3(18, 16), 256, 0, stream>>>(
        h, wb + (size_t)l * 3 * Dm * Dm, qkvb + l * 3 * Dm, qkv, vTg,
        Dm, Dm, 3 * Dm, 3 * Dm);
    attn_mfma<<<dim3(32, Hh, Bb), 128, 0, stream>>>(qkv, vTg, y);
    gemm_mfma<EPI_PART><<<dim3(6, 16, 2), 256, 0, stream>>>(
        y, wb + oPROJ + (size_t)l * Dm * Dm, nullptr, projPart, nullptr,
        Dm / 2, Dm, Dm, Dm);
    red_ln<<<ROWS, 256, 0, stream>>>(projPart, 2, projb + l * Dm, x,
                                     ln2w + l * Dm, ln2b + l * Dm, h);
    gemm_mfma<EPI_BIAS_GELU><<<dim3(32, 16), 256, 0, stream>>>(
        h, wb + oFF1 + (size_t)l * DFF * Dm, ff1b + l * DFF, ff, nullptr,
        Dm, Dm, DFF, DFF);
    gemm_mfma<EPI_PART><<<dim3(6, 16, 2), 256, 0, stream>>>(
        ff, wb + oFF2 + (size_t)l * Dm * DFF, nullptr, ff2Part, nullptr,
        DFF / 2, DFF, Dm, Dm);
    const float* nw = (l == Ll - 1) ? lnfw : ln1w + (l + 1) * Dm;
    const float* nb = (l == Ll - 1) ? lnfb : ln1b + (l + 1) * Dm;
    red_ln<<<ROWS, 256, 0, stream>>>(ff2Part, 2, ff2b + l * Dm, x, nw, nb, h);
  }

  gemm_mfma<EPI_NONE><<<dim3(393, 16), 256, 0, stream>>>(
      h, wb + oHEAD, nullptr, out, nullptr, Dm, Dm, Vv, Vv);
}

// Round 7
// 2225.397 us; speedup vs baseline: 1.0449x; 1.0089x over previous
//
#include <hip/hip_runtime.h>
#include <hip/hip_bf16.h>
#include <math.h>

#define Dm 768
#define Tt 1024
#define Bb 2
#define Hh 12
#define DFF 4096
#define Ll 12
#define Vv 50257
#define ROWS (Bb*Tt)   // 2048
#define LN_EPS 1e-5f

typedef unsigned int uint;
typedef unsigned short ushort;
typedef float f32x4 __attribute__((ext_vector_type(4)));
typedef short bf16x8 __attribute__((ext_vector_type(8)));
typedef ushort us8 __attribute__((ext_vector_type(8)));

__device__ __forceinline__ ushort f2bf(float f) {
  uint u = __builtin_bit_cast(uint, f);
  u += 0x7FFFu + ((u >> 16) & 1u);   // RNE
  return (ushort)(u >> 16);
}

#define GLL(gp, lp)                                                          \
  __builtin_amdgcn_global_load_lds(                                          \
      (const __attribute__((address_space(1))) uint*)(gp),                   \
      (__attribute__((address_space(3))) uint*)(lp), 16, 0, 0)

// ---------------------------------------------------------------------------
// Fused embedding + LayerNorm: x = tok[idx]+pos (fp32), h = LN(x) (bf16)
// ---------------------------------------------------------------------------
__global__ __launch_bounds__(256) void embed_ln(
    const int* __restrict__ idx, const float* __restrict__ tok,
    const float* __restrict__ pos, const float* __restrict__ w,
    const float* __restrict__ b, float* __restrict__ x,
    ushort* __restrict__ out) {
  const int row = blockIdx.x;
  const int t = row & (Tt - 1);
  const int tid = threadIdx.x;
  const float* tsrc = tok + (size_t)idx[row] * Dm;
  const float* psrc = pos + (size_t)t * Dm;
  float v[3];
  float sum = 0.f, sq = 0.f;
#pragma unroll
  for (int i = 0; i < 3; i++) {
    const int d = tid + i * 256;
    v[i] = tsrc[d] + psrc[d];
    x[(size_t)row * Dm + d] = v[i];
    sum += v[i]; sq += v[i] * v[i];
  }
#pragma unroll
  for (int off = 32; off > 0; off >>= 1) {
    sum += __shfl_xor(sum, off);
    sq  += __shfl_xor(sq, off);
  }
  __shared__ float red[8];
  const int wid = tid >> 6, lane = tid & 63;
  if (lane == 0) { red[wid] = sum; red[wid + 4] = sq; }
  __syncthreads();
  sum = red[0] + red[1] + red[2] + red[3];
  sq  = red[4] + red[5] + red[6] + red[7];
  const float mu = sum * (1.f / Dm);
  const float var = sq * (1.f / Dm) - mu * mu;
  const float rstd = rsqrtf(var + LN_EPS);
  ushort* dst = out + (size_t)row * Dm;
#pragma unroll
  for (int i = 0; i < 3; i++) {
    const int d = tid + i * 256;
    dst[d] = f2bf((v[i] - mu) * rstd * w[d] + b[d]);
  }
}

// ---------------------------------------------------------------------------
// Fused split-K reduce + bias + residual (x += ...) + LayerNorm -> bf16 h
// ---------------------------------------------------------------------------
__global__ __launch_bounds__(256) void red_ln(
    const float* __restrict__ part, int nsk, const float* __restrict__ bias,
    float* __restrict__ x, const float* __restrict__ w,
    const float* __restrict__ b, ushort* __restrict__ out) {
  const int row = blockIdx.x;
  const int tid = threadIdx.x;
  float v[3];
  float sum = 0.f, sq = 0.f;
#pragma unroll
  for (int i = 0; i < 3; i++) {
    const int d = tid + i * 256;
    const size_t off = (size_t)row * Dm + d;
    float s = x[off] + bias[d];
    for (int k = 0; k < nsk; k++) s += part[(size_t)k * ROWS * Dm + off];
    x[off] = s;
    v[i] = s;
    sum += s; sq += s * s;
  }
#pragma unroll
  for (int off = 32; off > 0; off >>= 1) {
    sum += __shfl_xor(sum, off);
    sq  += __shfl_xor(sq, off);
  }
  __shared__ float red[8];
  const int wid = tid >> 6, lane = tid & 63;
  if (lane == 0) { red[wid] = sum; red[wid + 4] = sq; }
  __syncthreads();
  sum = red[0] + red[1] + red[2] + red[3];
  sq  = red[4] + red[5] + red[6] + red[7];
  const float mu = sum * (1.f / Dm);
  const float var = sq * (1.f / Dm) - mu * mu;
  const float rstd = rsqrtf(var + LN_EPS);
  ushort* dst = out + (size_t)row * Dm;
#pragma unroll
  for (int i = 0; i < 3; i++) {
    const int d = tid + i * 256;
    dst[d] = f2bf((v[i] - mu) * rstd * w[d] + b[d]);
  }
}

// ---------------------------------------------------------------------------
// Weight converter fp32 -> bf16 (count in float4 units, contiguous)
// ---------------------------------------------------------------------------
__global__ __launch_bounds__(256) void convert_w(
    const float* __restrict__ s, ushort* __restrict__ d, int n4) {
  const int stride = gridDim.x * 256;
  for (int i = blockIdx.x * 256 + threadIdx.x; i < n4; i += stride) {
    const float4 v = ((const float4*)s)[i];
    ushort4 o;
    o.x = f2bf(v.x); o.y = f2bf(v.y); o.z = f2bf(v.z); o.w = f2bf(v.w);
    ((ushort4*)d)[i] = o;
  }
}

// ---------------------------------------------------------------------------
// bf16 MFMA GEMM (loop GEMMs): C[M,Nloc] = A[M,Kloop]@B^T + epi.
// ---------------------------------------------------------------------------
#define EPI_QKV 0
#define EPI_PART 1
#define EPI_BIAS_GELU 2
#define EPI_NONE 3

template <int EPI>
__global__ __launch_bounds__(256) void gemm_mfma(
    const ushort* __restrict__ A, const ushort* __restrict__ B,
    const float* __restrict__ bias, void* __restrict__ Cv,
    void* __restrict__ Cv2, int Kloop, int Kstr, int Nloc, int ldC) {
  __shared__ char lds[32768];           // 2 x (A 8KB + B 8KB)
  const int tid = threadIdx.x;
  const int l = tid & 63;
  const int wid = __builtin_amdgcn_readfirstlane(tid >> 6);
  const int wr = wid >> 1, wc = wid & 1;
  const int m0 = blockIdx.y * 128;
  const int n0 = blockIdx.x * 128;
  const int z = (EPI == EPI_PART) ? blockIdx.z : 0;
  if (EPI == EPI_PART) { A += (size_t)z * Kloop; B += (size_t)z * Kloop; }

  const int cperm = (((l & 3) ^ ((l >> 3) & 3)) * 8);
  const ushort* gA = A + (size_t)(m0 + wid * 32 + (l >> 2)) * Kstr + cperm;
  int rB = n0 + wid * 32 + (l >> 2);
  rB = min(rB, Nloc - 1);
  const ushort* gB = B + (size_t)rB * Kstr + cperm;

  const int rdSw = (l & 15) * 64 + (((l >> 4) ^ ((l >> 1) & 3)) * 16);
  const int aRd = wr * 4096 + rdSw;
  const int bRd = 8192 + wc * 4096 + rdSw;

  f32x4 acc[4][4] = {};
  const int nt = Kloop / 32;

  {
    const int lb = wid * 2048;
    GLL(gA, lds + lb);          GLL(gA + 16 * Kstr, lds + lb + 1024);
    GLL(gB, lds + 8192 + lb);   GLL(gB + 16 * Kstr, lds + 8192 + lb + 1024);
  }

  for (int t = 0; t < nt; ++t) {
    __syncthreads();
    if (t + 1 < nt) {
      const int base = ((t + 1) & 1) * 16384;
      const int lb = base + wid * 2048;
      const ushort* a = gA + (t + 1) * 32;
      const ushort* b = gB + (t + 1) * 32;
      GLL(a, lds + lb);         GLL(a + 16 * Kstr, lds + lb + 1024);
      GLL(b, lds + 8192 + lb);  GLL(b + 16 * Kstr, lds + 8192 + lb + 1024);
    }
    const int base = (t & 1) * 16384;
    bf16x8 av[4], bv[4];
#pragma unroll
    for (int i = 0; i < 4; ++i) {
      av[i] = *(const bf16x8*)(lds + base + aRd + i * 1024);
      bv[i] = *(const bf16x8*)(lds + base + bRd + i * 1024);
    }
#pragma unroll
    for (int i = 0; i < 4; ++i)
#pragma unroll
      for (int j = 0; j < 4; ++j)
        acc[i][j] = __builtin_amdgcn_mfma_f32_16x16x32_bf16(
            av[i], bv[j], acc[i][j], 0, 0, 0);
  }

#pragma unroll
  for (int fm = 0; fm < 4; ++fm) {
    const int row0 = m0 + wr * 64 + fm * 16 + (l >> 4) * 4;
#pragma unroll
    for (int fn = 0; fn < 4; ++fn) {
      const int col = n0 + wc * 64 + fn * 16 + (l & 15);
      if (col >= Nloc) continue;
      float bi = 0.f;
      if (EPI == EPI_QKV || EPI == EPI_BIAS_GELU) bi = bias[col];
      if (EPI == EPI_QKV && col >= 2 * Dm) {
        const int hh = (col - 2 * Dm) >> 6, dd = col & 63;
        const int bI = row0 >> 10, t0 = row0 & (Tt - 1);
        ushort4 o4;
        o4.x = f2bf(acc[fm][fn][0] + bi);
        o4.y = f2bf(acc[fm][fn][1] + bi);
        o4.z = f2bf(acc[fm][fn][2] + bi);
        o4.w = f2bf(acc[fm][fn][3] + bi);
        *(ushort4*)((ushort*)Cv2 +
                    ((size_t)((bI * Hh + hh) * 64 + dd)) * Tt + t0) = o4;
        continue;
      }
#pragma unroll
      for (int r = 0; r < 4; ++r) {
        float v = acc[fm][fn][r] + bi;
        const size_t off = (size_t)(row0 + r) * ldC + col;
        if (EPI == EPI_BIAS_GELU) {
          v = 0.5f * v * (1.f + erff(v * 0.70710678118654752f));
          ((ushort*)Cv)[off] = f2bf(v);
        } else if (EPI == EPI_QKV) {
          ((ushort*)Cv)[off] = f2bf(v);
        } else if (EPI == EPI_PART) {
          ((float*)Cv)[(size_t)z * ROWS * ldC + off] = v;
        } else {
          ((float*)Cv)[off] = v;
        }
      }
    }
  }
}

// ---------------------------------------------------------------------------
// Head GEMM, 256x256 tile, BK=32, 512 thr / 8 waves (2x4), 4 LDS buffers,
// counted vmcnt (8/4/0 tail-peel), one raw s_barrier per K-step (no drain),
// chunk-XOR LDS swizzle both-sides, XCD-chunked panel-major block swizzle.
// C[2048,50257] fp32 = A[2048,768] @ B[50257,768]^T.  grid 197*8=1576.
// ---------------------------------------------------------------------------
__global__ __launch_bounds__(512, 2) void gemm_head8(
    const ushort* __restrict__ A, const ushort* __restrict__ B,
    float* __restrict__ C) {
  __shared__ char lds[131072];          // 4 bufs x (A 16KB + B 16KB)
  const int tid = threadIdx.x;
  const int l = tid & 63;
  const int wid = __builtin_amdgcn_readfirstlane(tid >> 6);
  const int wm = wid >> 2, wn = wid & 3;

  // XCD-chunked panel-major swizzle (1576 = 197 panels x 8 m-rows, %8==0)
  const int bid = blockIdx.x;
  const int swz = (bid & 7) * 197 + (bid >> 3);
  const int pan = swz >> 3, mrw = swz & 7;
  const int m0 = mrw * 256;
  const int n0 = pan * 256;

  // staging sources: 4 GLL/thread per K-tile (A j=0,1; B j=0,1)
  // chunk c = tid + j*512; row r = c>>2, kchunk kq = c&3 (16B of 64B row)
  // source pre-swizzled: kq' = kq ^ (r&3)  (involution; reads use same XOR)
  const ushort* gA[2];
  const ushort* gB[2];
#pragma unroll
  for (int j = 0; j < 2; j++) {
    const int c = tid + j * 512;
    const int r = c >> 2, kq = c & 3;
    gA[j] = A + (size_t)(m0 + r) * Dm + ((kq ^ (r & 3)) * 8);
    int rb = n0 + r;
    rb = min(rb, Vv - 1);
    gB[j] = B + (size_t)rb * Dm + ((kq ^ (r & 3)) * 8);
  }

#define HSTAGE(t)                                                            \
  do {                                                                       \
    char* _lb = lds + ((t) & 3) * 32768;                                     \
    const int _o = (t) * 32;                                                 \
    GLL(gA[0] + _o, _lb + tid * 16);                                         \
    GLL(gA[1] + _o, _lb + 8192 + tid * 16);                                  \
    GLL(gB[0] + _o, _lb + 16384 + tid * 16);                                 \
    GLL(gB[1] + _o, _lb + 24576 + tid * 16);                                 \
  } while (0)

  f32x4 acc[8][4] = {};
  const int s = l & 15, g = l >> 4;

  // read offsets (within a buffer): A row = wm*128+fm*16+s, B row = wn*64+fn*16+s
  int aOff[8], bOff[4];
#pragma unroll
  for (int fm = 0; fm < 8; fm++) {
    const int r = wm * 128 + fm * 16 + s;
    aOff[fm] = r * 64 + ((g ^ (r & 3)) * 16);
  }
#pragma unroll
  for (int fn = 0; fn < 4; fn++) {
    const int r = wn * 64 + fn * 16 + s;
    bOff[fn] = 16384 + r * 64 + ((g ^ (r & 3)) * 16);
  }

  // prologue: stage t0,t1,t2 (12 loads); t0 resident after vmcnt(8)
  HSTAGE(0); HSTAGE(1); HSTAGE(2);
  asm volatile("s_waitcnt vmcnt(8)" ::: "memory");
  __builtin_amdgcn_s_barrier();
  __builtin_amdgcn_sched_barrier(0);

#define HITER(t, VC)                                                         \
  {                                                                          \
    if ((t) + 3 < 24) HSTAGE((t) + 3);                                       \
    char* bb = lds + ((t) & 3) * 32768;                                      \
    bf16x8 av[8], bv[4];                                                     \
    _Pragma("unroll")                                                        \
    for (int fm = 0; fm < 8; fm++) av[fm] = *(const bf16x8*)(bb + aOff[fm]); \
    _Pragma("unroll")                                                        \
    for (int fn = 0; fn < 4; fn++) bv[fn] = *(const bf16x8*)(bb + bOff[fn]); \
    __builtin_amdgcn_s_setprio(1);                                           \
    _Pragma("unroll")                                                        \
    for (int fm = 0; fm < 8; fm++)                                           \
      _Pragma("unroll")                                                      \
      for (int fn = 0; fn < 4; fn++)                                         \
        acc[fm][fn] = __builtin_amdgcn_mfma_f32_16x16x32_bf16(               \
            av[fm], bv[fn], acc[fm][fn], 0, 0, 0);                           \
    __builtin_amdgcn_s_setprio(0);                                           \
    asm volatile("s_waitcnt lgkmcnt(0)" ::: "memory");                       \
    asm volatile("s_waitcnt vmcnt(" #VC ")" ::: "memory");                   \
    __builtin_amdgcn_s_barrier();                                            \
    __builtin_amdgcn_sched_barrier(0);                                       \
  }

#pragma unroll 1
  for (int t = 0; t <= 20; ++t) HITER(t, 8);
  HITER(21, 4);
  HITER(22, 0);
  HITER(23, 0);

  // epilogue: C/D layout col=l&15 (B-row), row=(l>>4)*4+r (A-row)
#pragma unroll
  for (int fm = 0; fm < 8; ++fm) {
    const int row0 = m0 + wm * 128 + fm * 16 + g * 4;
#pragma unroll
    for (int fn = 0; fn < 4; ++fn) {
      const int col = n0 + wn * 64 + fn * 16 + s;
      if (col >= Vv) continue;
#pragma unroll
      for (int r = 0; r < 4; ++r)
        C[(size_t)(row0 + r) * Vv + col] = acc[fm][fn][r];
    }
  }
}

// ---------------------------------------------------------------------------
// MFMA flash attention. 128 thr = 2 waves; wave w owns q-rows bq*32+w*16..+15.
// ---------------------------------------------------------------------------
__global__ __launch_bounds__(128) void attn_mfma(
    const ushort* __restrict__ qkv, const ushort* __restrict__ vTg,
    ushort* __restrict__ y) {
  __shared__ char lds[36864];   // 2 x {K 8KB, VT 8KB} + P 2x2KB
  const int tid = threadIdx.x;
  const int l = tid & 63;
  const int w = tid >> 6;
  const int s = l & 15, g = l >> 4;
  const int bq = blockIdx.x, h = blockIdx.y, b = blockIdx.z;
  const int bh = b * Hh + h;

  const int qrow = bq * 32 + w * 16 + s;
  const ushort* qp = qkv + (size_t)(b * Tt + qrow) * 2304 + h * 64 + g * 8;
  const bf16x8 aq0 = *(const bf16x8*)qp;
  const bf16x8 aq1 = *(const bf16x8*)(qp + 32);

  size_t gofs[8];
#pragma unroll
  for (int i = 0; i < 8; i++) {
    const int c = tid + i * 128;
    if (i < 4) {
      const int kr = c >> 3;
      gofs[i] = (size_t)(b * Tt + kr) * 2304 + Dm + h * 64 + ((c & 7) ^ (kr & 7)) * 8;
    } else {
      const int cv = c - 512;
      const int vr = cv >> 3;
      gofs[i] = (size_t)(bh * 64 + vr) * Tt + ((cv & 7) ^ (vr & 7)) * 8;
    }
  }

#define ASTAGE(kt, base)                                                     \
  do {                                                                       \
    _Pragma("unroll")                                                        \
    for (int i = 0; i < 8; i++) {                                            \
      const ushort* p = (i < 4) ? (qkv + gofs[i] + (size_t)(kt) * 147456)    \
                                : (vTg + gofs[i] + (kt) * 64);               \
      GLL(p, lds + (base) + tid * 16 + i * 2048);                            \
    }                                                                        \
  } while (0)

  f32x4 oc[4] = {};
  float mrun[4], lrun[4];
#pragma unroll
  for (int r = 0; r < 4; r++) { mrun[r] = -INFINITY; lrun[r] = 0.f; }

  const int pB = 32768 + w * 2048;
  const int kSw = (s & 7);
  const int nkt = (bq >> 1) + 1;

  ASTAGE(0, 0);
  for (int kt = 0; kt < nkt; ++kt) {
    __syncthreads();
    if (kt + 1 < nkt) ASTAGE(kt + 1, ((kt + 1) & 1) * 16384);
    const int cur = (kt & 1) * 16384;

    f32x4 sc[4];
    __builtin_amdgcn_s_setprio(1);
#pragma unroll
    for (int jn = 0; jn < 4; jn++) {
      const int krow = cur + (jn * 16 + s) * 128;
      const bf16x8 bk0 = *(const bf16x8*)(lds + krow + ((g ^ kSw) * 16));
      const bf16x8 bk1 = *(const bf16x8*)(lds + krow + (((4 + g) ^ kSw) * 16));
      f32x4 z = {};
      z = __builtin_amdgcn_mfma_f32_16x16x32_bf16(aq0, bk0, z, 0, 0, 0);
      z = __builtin_amdgcn_mfma_f32_16x16x32_bf16(aq1, bk1, z, 0, 0, 0);
      sc[jn] = z;
    }
    __builtin_amdgcn_s_setprio(0);

    float cr[4];
    const bool diag = (kt == nkt - 1);
#pragma unroll
    for (int r = 0; r < 4; r++) {
      const int rowg = bq * 32 + w * 16 + g * 4 + r;
      float v[4];
#pragma unroll
      for (int jn = 0; jn < 4; jn++) {
        v[jn] = sc[jn][r] * 0.125f;
        if (diag && (kt * 64 + jn * 16 + s) > rowg) v[jn] = -INFINITY;
      }
      float mx = fmaxf(fmaxf(v[0], v[1]), fmaxf(v[2], v[3]));
      mx = fmaxf(mx, __shfl_xor(mx, 1));
      mx = fmaxf(mx, __shfl_xor(mx, 2));
      mx = fmaxf(mx, __shfl_xor(mx, 4));
      mx = fmaxf(mx, __shfl_xor(mx, 8));
      const float mnew = fmaxf(mrun[r], mx);
      const float corr = __expf(mrun[r] - mnew);
      mrun[r] = mnew;
      float ps = 0.f;
#pragma unroll
      for (int jn = 0; jn < 4; jn++) {
        const float p = __expf(v[jn] - mnew);
        ps += p;
        *(ushort*)(lds + pB + (g * 4 + r) * 128 +
                   (((2 * jn + (s >> 3)) ^ g) * 16) + (s & 7) * 2) = f2bf(p);
      }
      ps += __shfl_xor(ps, 1);
      ps += __shfl_xor(ps, 2);
      ps += __shfl_xor(ps, 4);
      ps += __shfl_xor(ps, 8);
      lrun[r] = lrun[r] * corr + ps;
      cr[r] = corr;
    }

    const float c01 = (s & 1) ? cr[1] : cr[0];
    const float c23 = (s & 1) ? cr[3] : cr[2];
    const float csel = (s & 2) ? c23 : c01;
    const float ccol = __shfl(csel, ((s >> 2) << 4) | s);
#pragma unroll
    for (int fm = 0; fm < 4; fm++) {
      oc[fm][0] *= ccol; oc[fm][1] *= ccol;
      oc[fm][2] *= ccol; oc[fm][3] *= ccol;
    }

    const bf16x8 bp0 = *(const bf16x8*)(lds + pB + s * 128 + ((g ^ (s >> 2)) * 16));
    const bf16x8 bp1 = *(const bf16x8*)(lds + pB + s * 128 + (((4 + g) ^ (s >> 2)) * 16));
    __builtin_amdgcn_s_setprio(1);
#pragma unroll
    for (int fm = 0; fm < 4; fm++) {
      const int vrow = cur + 8192 + (fm * 16 + s) * 128;
      const bf16x8 av0 = *(const bf16x8*)(lds + vrow + ((g ^ kSw) * 16));
      const bf16x8 av1 = *(const bf16x8*)(lds + vrow + (((4 + g) ^ kSw) * 16));
      oc[fm] = __builtin_amdgcn_mfma_f32_16x16x32_bf16(av0, bp0, oc[fm], 0, 0, 0);
      oc[fm] = __builtin_amdgcn_mfma_f32_16x16x32_bf16(av1, bp1, oc[fm], 0, 0, 0);
    }
    __builtin_amdgcn_s_setprio(0);
  }

  float li[4];
#pragma unroll
  for (int r = 0; r < 4; r++) li[r] = 1.f / lrun[r];
  const float l01 = (s & 1) ? li[1] : li[0];
  const float l23 = (s & 1) ? li[3] : li[2];
  const float lsel = (s & 2) ? l23 : l01;
  const float lcol = __shfl(lsel, ((s >> 2) << 4) | s);
  ushort* yp = y + (size_t)(b * Tt + qrow) * Dm + h * 64;
#pragma unroll
  for (int fm = 0; fm < 4; fm++) {
    ushort4 o4;
    o4.x = f2bf(oc[fm][0] * lcol);
    o4.y = f2bf(oc[fm][1] * lcol);
    o4.z = f2bf(oc[fm][2] * lcol);
    o4.w = f2bf(oc[fm][3] * lcol);
    *(ushort4*)(yp + fm * 16 + g * 4) = o4;
  }
}

// ---------------------------------------------------------------------------
extern "C" void kernel_launch(void* const* d_in, const int* in_sizes, int n_in,
                              void* d_out, int out_size, void* d_ws, size_t ws_size,
                              hipStream_t stream) {
  const int* idx = (const int*)d_in[0];
  const float* tok = (const float*)d_in[1];
  const float* pos = (const float*)d_in[2];
  const float* ln1w = (const float*)d_in[3];
  const float* ln1b = (const float*)d_in[4];
  const float* qkvw = (const float*)d_in[5];
  const float* qkvb = (const float*)d_in[6];
  const float* projw = (const float*)d_in[7];
  const float* projb = (const float*)d_in[8];
  const float* ln2w = (const float*)d_in[9];
  const float* ln2b = (const float*)d_in[10];
  const float* ff1w = (const float*)d_in[11];
  const float* ff1b = (const float*)d_in[12];
  const float* ff2w = (const float*)d_in[13];
  const float* ff2b = (const float*)d_in[14];
  const float* lnfw = (const float*)d_in[15];
  const float* lnfb = (const float*)d_in[16];
  const float* headw = (const float*)d_in[17];
  float* out = (float*)d_out;

  char* ws = (char*)d_ws;
  ushort* h    = (ushort*)ws;                    // [2048][768] bf16
  float*  x    = (float*)(ws + 3145728);         // [2048][768] fp32
  ushort* y    = (ushort*)(ws + 9437184);        // [2048][768] bf16
  ushort* qkv  = (ushort*)(ws + 12582912);       // [2048][2304] bf16
  ushort* vTg  = (ushort*)(ws + 22020096);       // [24][64][1024] bf16
  ushort* ff   = (ushort*)(ws + 25165824);       // [2048][4096] bf16
  ushort* wb   = (ushort*)(ws + 41943040);       // all weights bf16 (285MB)
  float* projPart = (float*)(ws + 12582912);     // 2x6.29MB over qkv+vT
  float* ff2Part  = (float*)(ws + 9437184);      // 2x6.29MB over y+qkv

  const size_t oPROJ = (size_t)Ll * 3 * Dm * Dm;           // 21233664
  const size_t oFF1  = oPROJ + (size_t)Ll * Dm * Dm;       // 28311552
  const size_t oFF2  = oFF1 + (size_t)Ll * DFF * Dm;       // 66060288
  const size_t oHEAD = oFF2 + (size_t)Ll * Dm * DFF;       // 103809024

  convert_w<<<2048, 256, 0, stream>>>(qkvw, wb, (int)(oPROJ / 4));
  convert_w<<<2048, 256, 0, stream>>>(projw, wb + oPROJ, (int)((oFF1 - oPROJ) / 4));
  convert_w<<<2048, 256, 0, stream>>>(ff1w, wb + oFF1, (int)((oFF2 - oFF1) / 4));
  convert_w<<<2048, 256, 0, stream>>>(ff2w, wb + oFF2, (int)((oHEAD - oFF2) / 4));
  convert_w<<<2048, 256, 0, stream>>>(headw, wb + oHEAD, (int)((size_t)Vv * Dm / 4));

  embed_ln<<<ROWS, 256, 0, stream>>>(idx, tok, pos, ln1w, ln1b, x, h);

  for (int l = 0; l < Ll; l++) {
    gemm_mfma<EPI_QKV><<<dim3(18, 16), 256, 0, stream>>>(
        h, wb + (size_t)l * 3 * Dm * Dm, qkvb + l * 3 * Dm, qkv, vTg,
        Dm, Dm, 3 * Dm, 3 * Dm);
    attn_mfma<<<dim3(32, Hh, Bb), 128, 0, stream>>>(qkv, vTg, y);
    gemm_mfma<EPI_PART><<<dim3(6, 16, 2), 256, 0, stream>>>(
        y, wb + oPROJ + (size_t)l * Dm * Dm, nullptr, projPart, nullptr,
        Dm / 2, Dm, Dm, Dm);
    red_ln<<<ROWS, 256, 0, stream>>>(projPart, 2, projb + l * Dm, x,
                                     ln2w + l * Dm, ln2b + l * Dm, h);
    gemm_mfma<EPI_BIAS_GELU><<<dim3(32, 16), 256, 0, stream>>>(
        h, wb + oFF1 + (size_t)l * DFF * Dm, ff1b + l * DFF, ff, nullptr,
        Dm, Dm, DFF, DFF);
    gemm_mfma<EPI_PART><<<dim3(6, 16, 2), 256, 0, stream>>>(
        ff, wb + oFF2 + (size_t)l * Dm * DFF, nullptr, ff2Part, nullptr,
        DFF / 2, DFF, Dm, Dm);
    const float* nw = (l == Ll - 1) ? lnfw : ln1w + (l + 1) * Dm;
    const float* nb = (l == Ll - 1) ? lnfb : ln1b + (l + 1) * Dm;
    red_ln<<<ROWS, 256, 0, stream>>>(ff2Part, 2, ff2b + l * Dm, x, nw, nb, h);
  }

  // head: 197 column panels x 8 m-rows
  gemm_head8<<<1576, 512, 0, stream>>>(h, wb + oHEAD, out);
}

// Round 8
// 2217.633 us; speedup vs baseline: 1.0485x; 1.0035x over previous
//
#include <hip/hip_runtime.h>
#include <hip/hip_bf16.h>
#include <math.h>

#define Dm 768
#define Tt 1024
#define Bb 2
#define Hh 12
#define DFF 4096
#define Ll 12
#define Vv 50257
#define ROWS (Bb*Tt)   // 2048
#define LN_EPS 1e-5f

typedef unsigned int uint;
typedef unsigned short ushort;
typedef float f32x4 __attribute__((ext_vector_type(4)));
typedef short bf16x8 __attribute__((ext_vector_type(8)));
typedef ushort us8 __attribute__((ext_vector_type(8)));

__device__ __forceinline__ ushort f2bf(float f) {
  uint u = __builtin_bit_cast(uint, f);
  u += 0x7FFFu + ((u >> 16) & 1u);   // RNE
  return (ushort)(u >> 16);
}

#define GLL(gp, lp)                                                          \
  __builtin_amdgcn_global_load_lds(                                          \
      (const __attribute__((address_space(1))) uint*)(gp),                   \
      (__attribute__((address_space(3))) uint*)(lp), 16, 0, 0)

// ---------------------------------------------------------------------------
// Fused embedding + LayerNorm: x = tok[idx]+pos (fp32), h = LN(x) (bf16)
// ---------------------------------------------------------------------------
__global__ __launch_bounds__(256) void embed_ln(
    const int* __restrict__ idx, const float* __restrict__ tok,
    const float* __restrict__ pos, const float* __restrict__ w,
    const float* __restrict__ b, float* __restrict__ x,
    ushort* __restrict__ out) {
  const int row = blockIdx.x;
  const int t = row & (Tt - 1);
  const int tid = threadIdx.x;
  const float* tsrc = tok + (size_t)idx[row] * Dm;
  const float* psrc = pos + (size_t)t * Dm;
  float v[3];
  float sum = 0.f, sq = 0.f;
#pragma unroll
  for (int i = 0; i < 3; i++) {
    const int d = tid + i * 256;
    v[i] = tsrc[d] + psrc[d];
    x[(size_t)row * Dm + d] = v[i];
    sum += v[i]; sq += v[i] * v[i];
  }
#pragma unroll
  for (int off = 32; off > 0; off >>= 1) {
    sum += __shfl_xor(sum, off);
    sq  += __shfl_xor(sq, off);
  }
  __shared__ float red[8];
  const int wid = tid >> 6, lane = tid & 63;
  if (lane == 0) { red[wid] = sum; red[wid + 4] = sq; }
  __syncthreads();
  sum = red[0] + red[1] + red[2] + red[3];
  sq  = red[4] + red[5] + red[6] + red[7];
  const float mu = sum * (1.f / Dm);
  const float var = sq * (1.f / Dm) - mu * mu;
  const float rstd = rsqrtf(var + LN_EPS);
  ushort* dst = out + (size_t)row * Dm;
#pragma unroll
  for (int i = 0; i < 3; i++) {
    const int d = tid + i * 256;
    dst[d] = f2bf((v[i] - mu) * rstd * w[d] + b[d]);
  }
}

// ---------------------------------------------------------------------------
// Fused split-K reduce + bias + residual (x += ...) + LayerNorm -> bf16 h
// ---------------------------------------------------------------------------
__global__ __launch_bounds__(256) void red_ln(
    const float* __restrict__ part, int nsk, const float* __restrict__ bias,
    float* __restrict__ x, const float* __restrict__ w,
    const float* __restrict__ b, ushort* __restrict__ out) {
  const int row = blockIdx.x;
  const int tid = threadIdx.x;
  float v[3];
  float sum = 0.f, sq = 0.f;
#pragma unroll
  for (int i = 0; i < 3; i++) {
    const int d = tid + i * 256;
    const size_t off = (size_t)row * Dm + d;
    float s = x[off] + bias[d];
    for (int k = 0; k < nsk; k++) s += part[(size_t)k * ROWS * Dm + off];
    x[off] = s;
    v[i] = s;
    sum += s; sq += s * s;
  }
#pragma unroll
  for (int off = 32; off > 0; off >>= 1) {
    sum += __shfl_xor(sum, off);
    sq  += __shfl_xor(sq, off);
  }
  __shared__ float red[8];
  const int wid = tid >> 6, lane = tid & 63;
  if (lane == 0) { red[wid] = sum; red[wid + 4] = sq; }
  __syncthreads();
  sum = red[0] + red[1] + red[2] + red[3];
  sq  = red[4] + red[5] + red[6] + red[7];
  const float mu = sum * (1.f / Dm);
  const float var = sq * (1.f / Dm) - mu * mu;
  const float rstd = rsqrtf(var + LN_EPS);
  ushort* dst = out + (size_t)row * Dm;
#pragma unroll
  for (int i = 0; i < 3; i++) {
    const int d = tid + i * 256;
    dst[d] = f2bf((v[i] - mu) * rstd * w[d] + b[d]);
  }
}

// ---------------------------------------------------------------------------
// Weight converter fp32 -> bf16 (count in float4 units, contiguous)
// ---------------------------------------------------------------------------
__global__ __launch_bounds__(256) void convert_w(
    const float* __restrict__ s, ushort* __restrict__ d, int n4) {
  const int stride = gridDim.x * 256;
  for (int i = blockIdx.x * 256 + threadIdx.x; i < n4; i += stride) {
    const float4 v = ((const float4*)s)[i];
    ushort4 o;
    o.x = f2bf(v.x); o.y = f2bf(v.y); o.z = f2bf(v.z); o.w = f2bf(v.w);
    ((ushort4*)d)[i] = o;
  }
}

// ---------------------------------------------------------------------------
// bf16 MFMA GEMM (loop GEMMs): C[M,Nloc] = A[M,Kloop]@B^T + epi.
// ---------------------------------------------------------------------------
#define EPI_QKV 0
#define EPI_PART 1
#define EPI_BIAS_GELU 2
#define EPI_NONE 3

template <int EPI>
__global__ __launch_bounds__(256) void gemm_mfma(
    const ushort* __restrict__ A, const ushort* __restrict__ B,
    const float* __restrict__ bias, void* __restrict__ Cv,
    void* __restrict__ Cv2, int Kloop, int Kstr, int Nloc, int ldC) {
  __shared__ char lds[32768];           // 2 x (A 8KB + B 8KB)
  const int tid = threadIdx.x;
  const int l = tid & 63;
  const int wid = __builtin_amdgcn_readfirstlane(tid >> 6);
  const int wr = wid >> 1, wc = wid & 1;
  const int m0 = blockIdx.y * 128;
  const int n0 = blockIdx.x * 128;
  const int z = (EPI == EPI_PART) ? blockIdx.z : 0;
  if (EPI == EPI_PART) { A += (size_t)z * Kloop; B += (size_t)z * Kloop; }

  const int cperm = (((l & 3) ^ ((l >> 3) & 3)) * 8);
  const ushort* gA = A + (size_t)(m0 + wid * 32 + (l >> 2)) * Kstr + cperm;
  int rB = n0 + wid * 32 + (l >> 2);
  rB = min(rB, Nloc - 1);
  const ushort* gB = B + (size_t)rB * Kstr + cperm;

  const int rdSw = (l & 15) * 64 + (((l >> 4) ^ ((l >> 1) & 3)) * 16);
  const int aRd = wr * 4096 + rdSw;
  const int bRd = 8192 + wc * 4096 + rdSw;

  f32x4 acc[4][4] = {};
  const int nt = Kloop / 32;

  {
    const int lb = wid * 2048;
    GLL(gA, lds + lb);          GLL(gA + 16 * Kstr, lds + lb + 1024);
    GLL(gB, lds + 8192 + lb);   GLL(gB + 16 * Kstr, lds + 8192 + lb + 1024);
  }

  for (int t = 0; t < nt; ++t) {
    __syncthreads();
    if (t + 1 < nt) {
      const int base = ((t + 1) & 1) * 16384;
      const int lb = base + wid * 2048;
      const ushort* a = gA + (t + 1) * 32;
      const ushort* b = gB + (t + 1) * 32;
      GLL(a, lds + lb);         GLL(a + 16 * Kstr, lds + lb + 1024);
      GLL(b, lds + 8192 + lb);  GLL(b + 16 * Kstr, lds + 8192 + lb + 1024);
    }
    const int base = (t & 1) * 16384;
    bf16x8 av[4], bv[4];
#pragma unroll
    for (int i = 0; i < 4; ++i) {
      av[i] = *(const bf16x8*)(lds + base + aRd + i * 1024);
      bv[i] = *(const bf16x8*)(lds + base + bRd + i * 1024);
    }
#pragma unroll
    for (int i = 0; i < 4; ++i)
#pragma unroll
      for (int j = 0; j < 4; ++j)
        acc[i][j] = __builtin_amdgcn_mfma_f32_16x16x32_bf16(
            av[i], bv[j], acc[i][j], 0, 0, 0);
  }

#pragma unroll
  for (int fm = 0; fm < 4; ++fm) {
    const int row0 = m0 + wr * 64 + fm * 16 + (l >> 4) * 4;
#pragma unroll
    for (int fn = 0; fn < 4; ++fn) {
      const int col = n0 + wc * 64 + fn * 16 + (l & 15);
      if (col >= Nloc) continue;
      float bi = 0.f;
      if (EPI == EPI_QKV || EPI == EPI_BIAS_GELU) bi = bias[col];
      if (EPI == EPI_QKV && col >= 2 * Dm) {
        const int hh = (col - 2 * Dm) >> 6, dd = col & 63;
        const int bI = row0 >> 10, t0 = row0 & (Tt - 1);
        ushort4 o4;
        o4.x = f2bf(acc[fm][fn][0] + bi);
        o4.y = f2bf(acc[fm][fn][1] + bi);
        o4.z = f2bf(acc[fm][fn][2] + bi);
        o4.w = f2bf(acc[fm][fn][3] + bi);
        *(ushort4*)((ushort*)Cv2 +
                    ((size_t)((bI * Hh + hh) * 64 + dd)) * Tt + t0) = o4;
        continue;
      }
#pragma unroll
      for (int r = 0; r < 4; ++r) {
        float v = acc[fm][fn][r] + bi;
        const size_t off = (size_t)(row0 + r) * ldC + col;
        if (EPI == EPI_BIAS_GELU) {
          v = 0.5f * v * (1.f + erff(v * 0.70710678118654752f));
          ((ushort*)Cv)[off] = f2bf(v);
        } else if (EPI == EPI_QKV) {
          ((ushort*)Cv)[off] = f2bf(v);
        } else if (EPI == EPI_PART) {
          ((float*)Cv)[(size_t)z * ROWS * ldC + off] = v;
        } else {
          ((float*)Cv)[off] = v;
        }
      }
    }
  }
}

// ---------------------------------------------------------------------------
// Head GEMM, 256x256 tile, BK=32, 512 thr / 8 waves (2x4), 4 LDS buffers,
// counted vmcnt, one raw s_barrier per K-step, XCD panel-major swizzle.
// LDS swizzle: chunk XOR (r>>1)&3 — independent of r&1 so bank-start covers
// 8 slots (2-way = free). R7 used (r&3) (correlated with r&1, 4-way, 1.45e7
// conflicts). Same involution on staging source and read side (rule 21).
// ---------------------------------------------------------------------------
__global__ __launch_bounds__(512, 2) void gemm_head8(
    const ushort* __restrict__ A, const ushort* __restrict__ B,
    float* __restrict__ C) {
  __shared__ char lds[131072];          // 4 bufs x (A 16KB + B 16KB)
  const int tid = threadIdx.x;
  const int l = tid & 63;
  const int wid = __builtin_amdgcn_readfirstlane(tid >> 6);
  const int wm = wid >> 2, wn = wid & 3;

  const int bid = blockIdx.x;
  const int swz = (bid & 7) * 197 + (bid >> 3);
  const int pan = swz >> 3, mrw = swz & 7;
  const int m0 = mrw * 256;
  const int n0 = pan * 256;

  const ushort* gA[2];
  const ushort* gB[2];
#pragma unroll
  for (int j = 0; j < 2; j++) {
    const int c = tid + j * 512;
    const int r = c >> 2, kq = c & 3;
    gA[j] = A + (size_t)(m0 + r) * Dm + ((kq ^ ((r >> 1) & 3)) * 8);
    int rb = n0 + r;
    rb = min(rb, Vv - 1);
    gB[j] = B + (size_t)rb * Dm + ((kq ^ ((r >> 1) & 3)) * 8);
  }

#define HSTAGE(t)                                                            \
  do {                                                                       \
    char* _lb = lds + ((t) & 3) * 32768;                                     \
    const int _o = (t) * 32;                                                 \
    GLL(gA[0] + _o, _lb + tid * 16);                                         \
    GLL(gA[1] + _o, _lb + 8192 + tid * 16);                                  \
    GLL(gB[0] + _o, _lb + 16384 + tid * 16);                                 \
    GLL(gB[1] + _o, _lb + 24576 + tid * 16);                                 \
  } while (0)

  f32x4 acc[8][4] = {};
  const int s = l & 15, g = l >> 4;

  int aOff[8], bOff[4];
#pragma unroll
  for (int fm = 0; fm < 8; fm++) {
    const int r = wm * 128 + fm * 16 + s;
    aOff[fm] = r * 64 + ((g ^ ((r >> 1) & 3)) * 16);
  }
#pragma unroll
  for (int fn = 0; fn < 4; fn++) {
    const int r = wn * 64 + fn * 16 + s;
    bOff[fn] = 16384 + r * 64 + ((g ^ ((r >> 1) & 3)) * 16);
  }

  HSTAGE(0); HSTAGE(1); HSTAGE(2);
  asm volatile("s_waitcnt vmcnt(8)" ::: "memory");
  __builtin_amdgcn_s_barrier();
  __builtin_amdgcn_sched_barrier(0);

#define HITER(t, VC)                                                         \
  {                                                                          \
    if ((t) + 3 < 24) HSTAGE((t) + 3);                                       \
    char* bb = lds + ((t) & 3) * 32768;                                      \
    bf16x8 av[8], bv[4];                                                     \
    _Pragma("unroll")                                                        \
    for (int fm = 0; fm < 8; fm++) av[fm] = *(const bf16x8*)(bb + aOff[fm]); \
    _Pragma("unroll")                                                        \
    for (int fn = 0; fn < 4; fn++) bv[fn] = *(const bf16x8*)(bb + bOff[fn]); \
    __builtin_amdgcn_s_setprio(1);                                           \
    _Pragma("unroll")                                                        \
    for (int fm = 0; fm < 8; fm++)                                           \
      _Pragma("unroll")                                                      \
      for (int fn = 0; fn < 4; fn++)                                         \
        acc[fm][fn] = __builtin_amdgcn_mfma_f32_16x16x32_bf16(               \
            av[fm], bv[fn], acc[fm][fn], 0, 0, 0);                           \
    __builtin_amdgcn_s_setprio(0);                                           \
    asm volatile("s_waitcnt lgkmcnt(0)" ::: "memory");                       \
    asm volatile("s_waitcnt vmcnt(" #VC ")" ::: "memory");                   \
    __builtin_amdgcn_s_barrier();                                            \
    __builtin_amdgcn_sched_barrier(0);                                       \
  }

#pragma unroll 1
  for (int t = 0; t <= 20; ++t) HITER(t, 8);
  HITER(21, 4);
  HITER(22, 0);
  HITER(23, 0);

#pragma unroll
  for (int fm = 0; fm < 8; ++fm) {
    const int row0 = m0 + wm * 128 + fm * 16 + g * 4;
#pragma unroll
    for (int fn = 0; fn < 4; ++fn) {
      const int col = n0 + wn * 64 + fn * 16 + s;
      if (col >= Vv) continue;
#pragma unroll
      for (int r = 0; r < 4; ++r)
        C[(size_t)(row0 + r) * Vv + col] = acc[fm][fn][r];
    }
  }
}

// ---------------------------------------------------------------------------
// MFMA flash attention. 128 thr = 2 waves; wave w owns q-rows bq*32+w*16..+15.
// bq reversed vs blockIdx so longest (most kv-tiles) blocks dispatch first.
// ---------------------------------------------------------------------------
__global__ __launch_bounds__(128) void attn_mfma(
    const ushort* __restrict__ qkv, const ushort* __restrict__ vTg,
    ushort* __restrict__ y) {
  __shared__ char lds[36864];   // 2 x {K 8KB, VT 8KB} + P 2x2KB
  const int tid = threadIdx.x;
  const int l = tid & 63;
  const int w = tid >> 6;
  const int s = l & 15, g = l >> 4;
  const int bq = gridDim.x - 1 - blockIdx.x;
  const int h = blockIdx.y, b = blockIdx.z;
  const int bh = b * Hh + h;

  const int qrow = bq * 32 + w * 16 + s;
  const ushort* qp = qkv + (size_t)(b * Tt + qrow) * 2304 + h * 64 + g * 8;
  const bf16x8 aq0 = *(const bf16x8*)qp;
  const bf16x8 aq1 = *(const bf16x8*)(qp + 32);

  size_t gofs[8];
#pragma unroll
  for (int i = 0; i < 8; i++) {
    const int c = tid + i * 128;
    if (i < 4) {
      const int kr = c >> 3;
      gofs[i] = (size_t)(b * Tt + kr) * 2304 + Dm + h * 64 + ((c & 7) ^ (kr & 7)) * 8;
    } else {
      const int cv = c - 512;
      const int vr = cv >> 3;
      gofs[i] = (size_t)(bh * 64 + vr) * Tt + ((cv & 7) ^ (vr & 7)) * 8;
    }
  }

#define ASTAGE(kt, base)                                                     \
  do {                                                                       \
    _Pragma("unroll")                                                        \
    for (int i = 0; i < 8; i++) {                                            \
      const ushort* p = (i < 4) ? (qkv + gofs[i] + (size_t)(kt) * 147456)    \
                                : (vTg + gofs[i] + (kt) * 64);               \
      GLL(p, lds + (base) + tid * 16 + i * 2048);                            \
    }                                                                        \
  } while (0)

  f32x4 oc[4] = {};
  float mrun[4], lrun[4];
#pragma unroll
  for (int r = 0; r < 4; r++) { mrun[r] = -INFINITY; lrun[r] = 0.f; }

  const int pB = 32768 + w * 2048;
  const int kSw = (s & 7);
  const int nkt = (bq >> 1) + 1;

  ASTAGE(0, 0);
  for (int kt = 0; kt < nkt; ++kt) {
    __syncthreads();
    if (kt + 1 < nkt) ASTAGE(kt + 1, ((kt + 1) & 1) * 16384);
    const int cur = (kt & 1) * 16384;

    f32x4 sc[4];
    __builtin_amdgcn_s_setprio(1);
#pragma unroll
    for (int jn = 0; jn < 4; jn++) {
      const int krow = cur + (jn * 16 + s) * 128;
      const bf16x8 bk0 = *(const bf16x8*)(lds + krow + ((g ^ kSw) * 16));
      const bf16x8 bk1 = *(const bf16x8*)(lds + krow + (((4 + g) ^ kSw) * 16));
      f32x4 z = {};
      z = __builtin_amdgcn_mfma_f32_16x16x32_bf16(aq0, bk0, z, 0, 0, 0);
      z = __builtin_amdgcn_mfma_f32_16x16x32_bf16(aq1, bk1, z, 0, 0, 0);
      sc[jn] = z;
    }
    __builtin_amdgcn_s_setprio(0);

    float cr[4];
    const bool diag = (kt == nkt - 1);
#pragma unroll
    for (int r = 0; r < 4; r++) {
      const int rowg = bq * 32 + w * 16 + g * 4 + r;
      float v[4];
#pragma unroll
      for (int jn = 0; jn < 4; jn++) {
        v[jn] = sc[jn][r] * 0.125f;
        if (diag && (kt * 64 + jn * 16 + s) > rowg) v[jn] = -INFINITY;
      }
      float mx = fmaxf(fmaxf(v[0], v[1]), fmaxf(v[2], v[3]));
      mx = fmaxf(mx, __shfl_xor(mx, 1));
      mx = fmaxf(mx, __shfl_xor(mx, 2));
      mx = fmaxf(mx, __shfl_xor(mx, 4));
      mx = fmaxf(mx, __shfl_xor(mx, 8));
      const float mnew = fmaxf(mrun[r], mx);
      const float corr = __expf(mrun[r] - mnew);
      mrun[r] = mnew;
      float ps = 0.f;
#pragma unroll
      for (int jn = 0; jn < 4; jn++) {
        const float p = __expf(v[jn] - mnew);
        ps += p;
        *(ushort*)(lds + pB + (g * 4 + r) * 128 +
                   (((2 * jn + (s >> 3)) ^ g) * 16) + (s & 7) * 2) = f2bf(p);
      }
      ps += __shfl_xor(ps, 1);
      ps += __shfl_xor(ps, 2);
      ps += __shfl_xor(ps, 4);
      ps += __shfl_xor(ps, 8);
      lrun[r] = lrun[r] * corr + ps;
      cr[r] = corr;
    }

    const float c01 = (s & 1) ? cr[1] : cr[0];
    const float c23 = (s & 1) ? cr[3] : cr[2];
    const float csel = (s & 2) ? c23 : c01;
    const float ccol = __shfl(csel, ((s >> 2) << 4) | s);
#pragma unroll
    for (int fm = 0; fm < 4; fm++) {
      oc[fm][0] *= ccol; oc[fm][1] *= ccol;
      oc[fm][2] *= ccol; oc[fm][3] *= ccol;
    }

    const bf16x8 bp0 = *(const bf16x8*)(lds + pB + s * 128 + ((g ^ (s >> 2)) * 16));
    const bf16x8 bp1 = *(const bf16x8*)(lds + pB + s * 128 + (((4 + g) ^ (s >> 2)) * 16));
    __builtin_amdgcn_s_setprio(1);
#pragma unroll
    for (int fm = 0; fm < 4; fm++) {
      const int vrow = cur + 8192 + (fm * 16 + s) * 128;
      const bf16x8 av0 = *(const bf16x8*)(lds + vrow + ((g ^ kSw) * 16));
      const bf16x8 av1 = *(const bf16x8*)(lds + vrow + (((4 + g) ^ kSw) * 16));
      oc[fm] = __builtin_amdgcn_mfma_f32_16x16x32_bf16(av0, bp0, oc[fm], 0, 0, 0);
      oc[fm] = __builtin_amdgcn_mfma_f32_16x16x32_bf16(av1, bp1, oc[fm], 0, 0, 0);
    }
    __builtin_amdgcn_s_setprio(0);
  }

  float li[4];
#pragma unroll
  for (int r = 0; r < 4; r++) li[r] = 1.f / lrun[r];
  const float l01 = (s & 1) ? li[1] : li[0];
  const float l23 = (s & 1) ? li[3] : li[2];
  const float lsel = (s & 2) ? l23 : l01;
  const float lcol = __shfl(lsel, ((s >> 2) << 4) | s);
  ushort* yp = y + (size_t)(b * Tt + qrow) * Dm + h * 64;
#pragma unroll
  for (int fm = 0; fm < 4; fm++) {
    ushort4 o4;
    o4.x = f2bf(oc[fm][0] * lcol);
    o4.y = f2bf(oc[fm][1] * lcol);
    o4.z = f2bf(oc[fm][2] * lcol);
    o4.w = f2bf(oc[fm][3] * lcol);
    *(ushort4*)(yp + fm * 16 + g * 4) = o4;
  }
}

// ---------------------------------------------------------------------------
extern "C" void kernel_launch(void* const* d_in, const int* in_sizes, int n_in,
                              void* d_out, int out_size, void* d_ws, size_t ws_size,
                              hipStream_t stream) {
  const int* idx = (const int*)d_in[0];
  const float* tok = (const float*)d_in[1];
  const float* pos = (const float*)d_in[2];
  const float* ln1w = (const float*)d_in[3];
  const float* ln1b = (const float*)d_in[4];
  const float* qkvw = (const float*)d_in[5];
  const float* qkvb = (const float*)d_in[6];
  const float* projw = (const float*)d_in[7];
  const float* projb = (const float*)d_in[8];
  const float* ln2w = (const float*)d_in[9];
  const float* ln2b = (const float*)d_in[10];
  const float* ff1w = (const float*)d_in[11];
  const float* ff1b = (const float*)d_in[12];
  const float* ff2w = (const float*)d_in[13];
  const float* ff2b = (const float*)d_in[14];
  const float* lnfw = (const float*)d_in[15];
  const float* lnfb = (const float*)d_in[16];
  const float* headw = (const float*)d_in[17];
  float* out = (float*)d_out;

  char* ws = (char*)d_ws;
  ushort* h    = (ushort*)ws;                    // [2048][768] bf16
  float*  x    = (float*)(ws + 3145728);         // [2048][768] fp32
  ushort* y    = (ushort*)(ws + 9437184);        // [2048][768] bf16
  ushort* qkv  = (ushort*)(ws + 12582912);       // [2048][2304] bf16
  ushort* vTg  = (ushort*)(ws + 22020096);       // [24][64][1024] bf16
  ushort* ff   = (ushort*)(ws + 25165824);       // [2048][4096] bf16
  ushort* wb   = (ushort*)(ws + 41943040);       // all weights bf16 (285MB)
  float* projPart = (float*)(ws + 12582912);     // 2x6.29MB over qkv+vT
  float* ff2Part  = (float*)(ws + 9437184);      // 2x6.29MB over y+qkv

  const size_t oPROJ = (size_t)Ll * 3 * Dm * Dm;           // 21233664
  const size_t oFF1  = oPROJ + (size_t)Ll * Dm * Dm;       // 28311552
  const size_t oFF2  = oFF1 + (size_t)Ll * DFF * Dm;       // 66060288
  const size_t oHEAD = oFF2 + (size_t)Ll * Dm * DFF;       // 103809024

  convert_w<<<2048, 256, 0, stream>>>(qkvw, wb, (int)(oPROJ / 4));
  convert_w<<<2048, 256, 0, stream>>>(projw, wb + oPROJ, (int)((oFF1 - oPROJ) / 4));
  convert_w<<<2048, 256, 0, stream>>>(ff1w, wb + oFF1, (int)((oFF2 - oFF1) / 4));
  convert_w<<<2048, 256, 0, stream>>>(ff2w, wb + oFF2, (int)((oHEAD - oFF2) / 4));
  convert_w<<<2048, 256, 0, stream>>>(headw, wb + oHEAD, (int)((size_t)Vv * Dm / 4));

  embed_ln<<<ROWS, 256, 0, stream>>>(idx, tok, pos, ln1w, ln1b, x, h);

  for (int l = 0; l < Ll; l++) {
    gemm_mfma<EPI_QKV><<<dim3(18, 16), 256, 0, stream>>>(
        h, wb + (size_t)l * 3 * Dm * Dm, qkvb + l * 3 * Dm, qkv, vTg,
        Dm, Dm, 3 * Dm, 3 * Dm);
    attn_mfma<<<dim3(32, Hh, Bb), 128, 0, stream>>>(qkv, vTg, y);
    gemm_mfma<EPI_PART><<<dim3(6, 16, 2), 256, 0, stream>>>(
        y, wb + oPROJ + (size_t)l * Dm * Dm, nullptr, projPart, nullptr,
        Dm / 2, Dm, Dm, Dm);
    red_ln<<<ROWS, 256, 0, stream>>>(projPart, 2, projb + l * Dm, x,
                                     ln2w + l * Dm, ln2b + l * Dm, h);
    gemm_mfma<EPI_BIAS_GELU><<<dim3(32, 16), 256, 0, stream>>>(
        h, wb + oFF1 + (size_t)l * DFF * Dm, ff1b + l * DFF, ff, nullptr,
        Dm, Dm, DFF, DFF);
    gemm_mfma<EPI_PART><<<dim3(6, 16, 2), 256, 0, stream>>>(
        ff, wb + oFF2 + (size_t)l * Dm * DFF, nullptr, ff2Part, nullptr,
        DFF / 2, DFF, Dm, Dm);
    const float* nw = (l == Ll - 1) ? lnfw : ln1w + (l + 1) * Dm;
    const float* nb = (l == Ll - 1) ? lnfb : ln1b + (l + 1) * Dm;
    red_ln<<<ROWS, 256, 0, stream>>>(ff2Part, 2, ff2b + l * Dm, x, nw, nb, h);
  }

  gemm_head8<<<1576, 512, 0, stream>>>(h, wb + oHEAD, out);
}